// Round 1
// baseline (3604.118 us; speedup 1.0000x reference)
//
#include <hip/hip_runtime.h>

#define NN 20000
#define NE 640000
#define HD 128
#define NL 3
#define NG 128
#define NC 2
#define BN_EPS 1e-5f

// ---------- encoder: h = x*enc_W + enc_b ; z = (1+eps0)*h ----------
__global__ void k_enc(const float* __restrict__ x, const float* __restrict__ W,
                      const float* __restrict__ b, const float* __restrict__ eps_gin,
                      float* __restrict__ h, float* __restrict__ z) {
    int i = blockIdx.x * blockDim.x + threadIdx.x;   // over NN*32 float4 slots
    if (i >= NN * (HD / 4)) return;
    int n  = i >> 5;
    int c4 = (i & 31) * 4;
    float xv = x[n];
    float e  = 1.0f + eps_gin[0];
    float4 w  = *(const float4*)&W[c4];
    float4 bb = *(const float4*)&b[c4];
    float4 hv;
    hv.x = fmaf(xv, w.x, bb.x);
    hv.y = fmaf(xv, w.y, bb.y);
    hv.z = fmaf(xv, w.z, bb.z);
    hv.w = fmaf(xv, w.w, bb.w);
    *(float4*)&h[n * HD + c4] = hv;
    float4 zv = { e * hv.x, e * hv.y, e * hv.z, e * hv.w };
    *(float4*)&z[n * HD + c4] = zv;
}

// ---------- edge scatter: z[dst] += h[src] ----------
__global__ void k_scatter(const int* __restrict__ ei, const float* __restrict__ h,
                          float* __restrict__ z) {
    int i = blockIdx.x * blockDim.x + threadIdx.x;   // over NE*32 float4 slots
    if (i >= NE * (HD / 4)) return;
    int e  = i >> 5;
    int c4 = (i & 31) * 4;
    int s = ei[e];
    int d = ei[NE + e];
    float4 v = *(const float4*)&h[s * HD + c4];
    float* zp = &z[d * HD + c4];
    atomicAdd(zp + 0, v.x);
    atomicAdd(zp + 1, v.y);
    atomicAdd(zp + 2, v.z);
    atomicAdd(zp + 3, v.w);
}

// ---------- GEMM: out = f(A) @ W, plus per-column sum/sumsq stats ----------
// f(A) = A (BNRELU=false) or relu(scale[k]*A + shift[k]) (BNRELU=true).
// Biases of the Linear layers are skipped: they cancel in the following BN.
// Tile: 64 rows x 128 cols per block, 256 threads, each thread 8x4 outputs.
template <bool BNRELU>
__global__ __launch_bounds__(256) void k_gemm(
    const float* __restrict__ A, const float* __restrict__ W,
    const float* __restrict__ scale, const float* __restrict__ shift,
    float* __restrict__ out, float* __restrict__ colsum, float* __restrict__ colsq) {
    __shared__ __align__(16) float smem[32 * 64 + 32 * 128];  // 24 KB
    float* As = smem;          // [k][row]  32 x 64 (transposed)
    float* Ws = smem + 2048;   // [k][col]  32 x 128

    int tid = threadIdx.x;
    int tx = tid & 31;         // col group (4 cols)
    int ty = tid >> 5;         // row group (8 rows)
    int r0 = blockIdx.x * 64;

    float acc[8][4];
#pragma unroll
    for (int i = 0; i < 8; i++)
#pragma unroll
        for (int j = 0; j < 4; j++) acc[i][j] = 0.0f;

    for (int k0 = 0; k0 < HD; k0 += 32) {
        // stage W chunk: 32x128 floats, coalesced float4
#pragma unroll
        for (int i = 0; i < 4; i++) {
            int f = tid + i * 256;          // float4 id 0..1023
            int k = f >> 5;
            int c = (f & 31) * 4;
            *(float4*)&Ws[k * 128 + c] = *(const float4*)&W[(k0 + k) * HD + c];
        }
        // stage A chunk: 64 rows x 32 k, transposed into As[k][row]
#pragma unroll
        for (int i = 0; i < 2; i++) {
            int f = tid + i * 256;          // 0..511
            int r = f >> 3;
            int kq = (f & 7) * 4;
            int row = r0 + r;
            float4 v = { 0.f, 0.f, 0.f, 0.f };
            if (row < NN) v = *(const float4*)&A[row * HD + k0 + kq];
            if (BNRELU) {
                v.x = fmaxf(fmaf(scale[k0 + kq + 0], v.x, shift[k0 + kq + 0]), 0.f);
                v.y = fmaxf(fmaf(scale[k0 + kq + 1], v.y, shift[k0 + kq + 1]), 0.f);
                v.z = fmaxf(fmaf(scale[k0 + kq + 2], v.z, shift[k0 + kq + 2]), 0.f);
                v.w = fmaxf(fmaf(scale[k0 + kq + 3], v.w, shift[k0 + kq + 3]), 0.f);
            }
            As[(kq + 0) * 64 + r] = v.x;
            As[(kq + 1) * 64 + r] = v.y;
            As[(kq + 2) * 64 + r] = v.z;
            As[(kq + 3) * 64 + r] = v.w;
        }
        __syncthreads();
#pragma unroll
        for (int k = 0; k < 32; k++) {
            float4 wv  = *(float4*)&Ws[k * 128 + tx * 4];
            float4 av0 = *(float4*)&As[k * 64 + ty * 8];
            float4 av1 = *(float4*)&As[k * 64 + ty * 8 + 4];
            float ar[8] = { av0.x, av0.y, av0.z, av0.w, av1.x, av1.y, av1.z, av1.w };
            float wr[4] = { wv.x, wv.y, wv.z, wv.w };
#pragma unroll
            for (int i = 0; i < 8; i++)
#pragma unroll
                for (int j = 0; j < 4; j++)
                    acc[i][j] = fmaf(ar[i], wr[j], acc[i][j]);
        }
        __syncthreads();
    }

    // write outputs + per-thread column partial stats
    float s[4] = { 0, 0, 0, 0 }, q[4] = { 0, 0, 0, 0 };
#pragma unroll
    for (int i = 0; i < 8; i++) {
        int row = r0 + ty * 8 + i;
        if (row < NN) {
            float4 o = { acc[i][0], acc[i][1], acc[i][2], acc[i][3] };
            *(float4*)&out[row * HD + tx * 4] = o;
#pragma unroll
            for (int j = 0; j < 4; j++) {
                s[j] += acc[i][j];
                q[j] = fmaf(acc[i][j], acc[i][j], q[j]);
            }
        }
    }
    // block-level stats reduction in LDS (reuse smem), one atomic per col
    float* ssum = smem;          // [8][128]
    float* ssq  = smem + 1024;   // [8][128]
#pragma unroll
    for (int j = 0; j < 4; j++) {
        ssum[ty * 128 + tx * 4 + j] = s[j];
        ssq[ty * 128 + tx * 4 + j]  = q[j];
    }
    __syncthreads();
    if (tid < 128) {
        float ss = 0.f, qq = 0.f;
#pragma unroll
        for (int i = 0; i < 8; i++) {
            ss += ssum[i * 128 + tid];
            qq += ssq[i * 128 + tid];
        }
        atomicAdd(&colsum[tid], ss);
        atomicAdd(&colsq[tid], qq);
    }
}

// ---------- BN finalize: scale/shift from column stats ----------
__global__ void k_bnfin(const float* __restrict__ colsum, const float* __restrict__ colsq,
                        const float* __restrict__ gamma, const float* __restrict__ beta,
                        float* __restrict__ scale, float* __restrict__ shift) {
    int c = threadIdx.x;
    float mu  = colsum[c] * (1.0f / NN);
    float var = colsq[c] * (1.0f / NN) - mu * mu;
    float a = gamma[c] * rsqrtf(var + BN_EPS);
    scale[c] = a;
    shift[c] = beta[c] - a * mu;
}

// ---------- post: h = relu(scale*u+shift); z = (1+eps_next)*h OR pool ----------
template <bool WRITE_Z>
__global__ void k_post(const float* __restrict__ u, const float* __restrict__ scale,
                       const float* __restrict__ shift, const float* __restrict__ eps_gin,
                       int next_l, float* __restrict__ h, float* __restrict__ z,
                       const int* __restrict__ batch, float* __restrict__ pooled,
                       float* __restrict__ cnt) {
    int i = blockIdx.x * blockDim.x + threadIdx.x;   // NN*32
    if (i >= NN * (HD / 4)) return;
    int n  = i >> 5;
    int c4 = (i & 31) * 4;
    float4 uv = *(const float4*)&u[n * HD + c4];
    float4 sc = *(const float4*)&scale[c4];
    float4 sh = *(const float4*)&shift[c4];
    float4 hv;
    hv.x = fmaxf(fmaf(sc.x, uv.x, sh.x), 0.f);
    hv.y = fmaxf(fmaf(sc.y, uv.y, sh.y), 0.f);
    hv.z = fmaxf(fmaf(sc.z, uv.z, sh.z), 0.f);
    hv.w = fmaxf(fmaf(sc.w, uv.w, sh.w), 0.f);
    if (WRITE_Z) {
        *(float4*)&h[n * HD + c4] = hv;
        float e = 1.0f + eps_gin[next_l];
        float4 zv = { e * hv.x, e * hv.y, e * hv.z, e * hv.w };
        *(float4*)&z[n * HD + c4] = zv;   // in-place over u: elementwise-safe
    } else {
        int g = batch[n];
        float* pp = &pooled[g * HD + c4];
        atomicAdd(pp + 0, hv.x);
        atomicAdd(pp + 1, hv.y);
        atomicAdd(pp + 2, hv.z);
        atomicAdd(pp + 3, hv.w);
        if (c4 == 0) atomicAdd(&cnt[g], 1.0f);
    }
}

// ---------- classifier ----------
__global__ void k_cls(const float* __restrict__ pooled, const float* __restrict__ cnt,
                      const float* __restrict__ Wc, const float* __restrict__ bc,
                      float* __restrict__ out) {
    int t = threadIdx.x;          // 256 threads = 128 graphs x 2 classes
    int g = t >> 1, c = t & 1;
    float inv = 1.0f / fmaxf(cnt[g], 1.0f);
    float acc = bc[c];
    for (int k = 0; k < HD; k++)
        acc = fmaf(pooled[g * HD + k] * inv, Wc[k * NC + c], acc);
    out[g * NC + c] = acc;
}

extern "C" void kernel_launch(void* const* d_in, const int* in_sizes, int n_in,
                              void* d_out, int out_size, void* d_ws, size_t ws_size,
                              hipStream_t stream) {
    const float* x      = (const float*)d_in[0];
    const int*   ei     = (const int*)d_in[1];
    const int*   batch  = (const int*)d_in[2];
    const float* enc_W  = (const float*)d_in[3];
    const float* enc_b  = (const float*)d_in[4];
    const float* W1     = (const float*)d_in[5];
    // d_in[6] = b1 (cancels in BN), d_in[10] = b2 (cancels in BN)
    const float* g1     = (const float*)d_in[7];
    const float* be1    = (const float*)d_in[8];
    const float* W2     = (const float*)d_in[9];
    const float* eps_g  = (const float*)d_in[11];
    const float* bn_g   = (const float*)d_in[12];
    const float* bn_b   = (const float*)d_in[13];
    const float* cls_W  = (const float*)d_in[14];
    const float* cls_b  = (const float*)d_in[15];
    float* out = (float*)d_out;

    float* ws     = (float*)d_ws;
    float* h      = ws;                    // NN*HD
    float* z      = h + NN * HD;           // NN*HD (also reused as u)
    float* t      = z + NN * HD;           // NN*HD
    float* stats  = t + NN * HD;           // 6*256 (sum|sumsq per BN instance)
    float* scsh   = stats + 6 * 256;       // 6*256 (scale|shift per BN instance)
    float* pooled = scsh + 6 * 256;        // NG*HD
    float* cnt    = pooled + NG * HD;      // NG

    hipMemsetAsync(stats, 0, 6 * 256 * sizeof(float), stream);
    hipMemsetAsync(pooled, 0, (NG * HD + NG) * sizeof(float), stream);

    dim3 b256(256);
    const int nwork = NN * (HD / 4);       // 640000
    const int ework = NE * (HD / 4);       // 20480000
    const int gemm_blocks = (NN + 63) / 64;  // 313

    k_enc<<<(nwork + 255) / 256, b256, 0, stream>>>(x, enc_W, enc_b, eps_g, h, z);

    for (int l = 0; l < NL; l++) {
        int u1 = l * 2, u2 = l * 2 + 1;
        k_scatter<<<(ework + 255) / 256, b256, 0, stream>>>(ei, h, z);
        k_gemm<false><<<gemm_blocks, b256, 0, stream>>>(
            z, W1 + l * HD * HD, nullptr, nullptr, t,
            stats + u1 * 256, stats + u1 * 256 + 128);
        k_bnfin<<<1, 128, 0, stream>>>(stats + u1 * 256, stats + u1 * 256 + 128,
                                       g1 + l * HD, be1 + l * HD,
                                       scsh + u1 * 256, scsh + u1 * 256 + 128);
        k_gemm<true><<<gemm_blocks, b256, 0, stream>>>(
            t, W2 + l * HD * HD, scsh + u1 * 256, scsh + u1 * 256 + 128, z,
            stats + u2 * 256, stats + u2 * 256 + 128);
        k_bnfin<<<1, 128, 0, stream>>>(stats + u2 * 256, stats + u2 * 256 + 128,
                                       bn_g + l * HD, bn_b + l * HD,
                                       scsh + u2 * 256, scsh + u2 * 256 + 128);
        if (l < NL - 1) {
            k_post<true><<<(nwork + 255) / 256, b256, 0, stream>>>(
                z, scsh + u2 * 256, scsh + u2 * 256 + 128, eps_g, l + 1,
                h, z, nullptr, nullptr, nullptr);
        } else {
            k_post<false><<<(nwork + 255) / 256, b256, 0, stream>>>(
                z, scsh + u2 * 256, scsh + u2 * 256 + 128, eps_g, 0,
                nullptr, nullptr, batch, pooled, cnt);
        }
    }
    k_cls<<<1, 256, 0, stream>>>(pooled, cnt, cls_W, cls_b, out);
}

// Round 2
// 607.759 us; speedup vs baseline: 5.9302x; 5.9302x over previous
//
#include <hip/hip_runtime.h>

#define NN 20000
#define NE 640000
#define HD 128
#define NL 3
#define NG 128
#define NC 2
#define BN_EPS 1e-5f

// ---------- CSR build: histogram of dst ----------
__global__ void k_hist(const int* __restrict__ ei, int* __restrict__ counts) {
    int e = blockIdx.x * blockDim.x + threadIdx.x;
    if (e >= NE) return;
    atomicAdd(&counts[ei[NE + e]], 1);
}

// ---------- CSR build: exclusive scan of counts -> row_ptr, cursor ----------
__global__ __launch_bounds__(1024) void k_scan(const int* __restrict__ counts,
                                               int* __restrict__ row_ptr,
                                               int* __restrict__ cursor) {
    __shared__ int sdata[1024];
    __shared__ int carry;
    int tid = threadIdx.x;
    if (tid == 0) carry = 0;
    __syncthreads();
    for (int base = 0; base < NN; base += 1024) {
        int i = base + tid;
        int v = (i < NN) ? counts[i] : 0;
        sdata[tid] = v;
        __syncthreads();
        for (int off = 1; off < 1024; off <<= 1) {
            int t = (tid >= off) ? sdata[tid - off] : 0;
            __syncthreads();
            sdata[tid] += t;
            __syncthreads();
        }
        int carry_local = carry;
        int excl = sdata[tid] - v;
        if (i < NN) {
            row_ptr[i] = carry_local + excl;
            cursor[i]  = carry_local + excl;
        }
        __syncthreads();
        if (tid == 0) carry = carry_local + sdata[1023];
        __syncthreads();
    }
    if (tid == 0) row_ptr[NN] = NE;
}

// ---------- CSR build: fill source lists ----------
__global__ void k_fill(const int* __restrict__ ei, int* __restrict__ cursor,
                       int* __restrict__ csr_src) {
    int e = blockIdx.x * blockDim.x + threadIdx.x;
    if (e >= NE) return;
    int pos = atomicAdd(&cursor[ei[NE + e]], 1);
    csr_src[pos] = ei[e];
}

// ---------- encoder: h = x*enc_W + enc_b ----------
__global__ void k_enc(const float* __restrict__ x, const float* __restrict__ W,
                      const float* __restrict__ b, float* __restrict__ h) {
    int i = blockIdx.x * blockDim.x + threadIdx.x;   // over NN*32 float4 slots
    if (i >= NN * (HD / 4)) return;
    int n  = i >> 5;
    int c4 = (i & 31) * 4;
    float xv = x[n];
    float4 w  = *(const float4*)&W[c4];
    float4 bb = *(const float4*)&b[c4];
    float4 hv;
    hv.x = fmaf(xv, w.x, bb.x);
    hv.y = fmaf(xv, w.y, bb.y);
    hv.z = fmaf(xv, w.z, bb.z);
    hv.w = fmaf(xv, w.w, bb.w);
    *(float4*)&h[n * HD + c4] = hv;
}

// ---------- aggregation (gather): z[n] = (1+eps_l)*h[n] + sum_{s in N(n)} h[s] ----------
__global__ void k_aggr(const int* __restrict__ row_ptr, const int* __restrict__ csr_src,
                       const float* __restrict__ h, const float* __restrict__ eps_gin,
                       int l, float* __restrict__ z) {
    int i = blockIdx.x * blockDim.x + threadIdx.x;   // NN*32
    if (i >= NN * (HD / 4)) return;
    int n  = i >> 5;
    int c4 = (i & 31) * 4;
    float e = 1.0f + eps_gin[l];
    float4 hv = *(const float4*)&h[n * HD + c4];
    float4 acc = { e * hv.x, e * hv.y, e * hv.z, e * hv.w };
    int p   = row_ptr[n];
    int end = row_ptr[n + 1];
    for (; p + 1 < end; p += 2) {
        int s0 = csr_src[p];
        int s1 = csr_src[p + 1];
        float4 v0 = *(const float4*)&h[s0 * HD + c4];
        float4 v1 = *(const float4*)&h[s1 * HD + c4];
        acc.x += v0.x + v1.x;
        acc.y += v0.y + v1.y;
        acc.z += v0.z + v1.z;
        acc.w += v0.w + v1.w;
    }
    if (p < end) {
        int s0 = csr_src[p];
        float4 v0 = *(const float4*)&h[s0 * HD + c4];
        acc.x += v0.x; acc.y += v0.y; acc.z += v0.z; acc.w += v0.w;
    }
    *(float4*)&z[n * HD + c4] = acc;
}

// ---------- GEMM: out = f(A) @ W, plus per-column sum/sumsq stats ----------
// f(A) = A (BNRELU=false) or relu(scale[k]*A + shift[k]) (BNRELU=true).
// Biases of the Linear layers are skipped: they cancel in the following BN.
template <bool BNRELU>
__global__ __launch_bounds__(256) void k_gemm(
    const float* __restrict__ A, const float* __restrict__ W,
    const float* __restrict__ scale, const float* __restrict__ shift,
    float* __restrict__ out, float* __restrict__ colsum, float* __restrict__ colsq) {
    __shared__ __align__(16) float smem[32 * 64 + 32 * 128];  // 24 KB
    float* As = smem;          // [k][row]  32 x 64 (transposed)
    float* Ws = smem + 2048;   // [k][col]  32 x 128

    int tid = threadIdx.x;
    int tx = tid & 31;         // col group (4 cols)
    int ty = tid >> 5;         // row group (8 rows)
    int r0 = blockIdx.x * 64;

    float acc[8][4];
#pragma unroll
    for (int i = 0; i < 8; i++)
#pragma unroll
        for (int j = 0; j < 4; j++) acc[i][j] = 0.0f;

    for (int k0 = 0; k0 < HD; k0 += 32) {
#pragma unroll
        for (int i = 0; i < 4; i++) {
            int f = tid + i * 256;          // float4 id 0..1023
            int k = f >> 5;
            int c = (f & 31) * 4;
            *(float4*)&Ws[k * 128 + c] = *(const float4*)&W[(k0 + k) * HD + c];
        }
#pragma unroll
        for (int i = 0; i < 2; i++) {
            int f = tid + i * 256;          // 0..511
            int r = f >> 3;
            int kq = (f & 7) * 4;
            int row = r0 + r;
            float4 v = { 0.f, 0.f, 0.f, 0.f };
            if (row < NN) v = *(const float4*)&A[row * HD + k0 + kq];
            if (BNRELU) {
                v.x = fmaxf(fmaf(scale[k0 + kq + 0], v.x, shift[k0 + kq + 0]), 0.f);
                v.y = fmaxf(fmaf(scale[k0 + kq + 1], v.y, shift[k0 + kq + 1]), 0.f);
                v.z = fmaxf(fmaf(scale[k0 + kq + 2], v.z, shift[k0 + kq + 2]), 0.f);
                v.w = fmaxf(fmaf(scale[k0 + kq + 3], v.w, shift[k0 + kq + 3]), 0.f);
            }
            As[(kq + 0) * 64 + r] = v.x;
            As[(kq + 1) * 64 + r] = v.y;
            As[(kq + 2) * 64 + r] = v.z;
            As[(kq + 3) * 64 + r] = v.w;
        }
        __syncthreads();
#pragma unroll
        for (int k = 0; k < 32; k++) {
            float4 wv  = *(float4*)&Ws[k * 128 + tx * 4];
            float4 av0 = *(float4*)&As[k * 64 + ty * 8];
            float4 av1 = *(float4*)&As[k * 64 + ty * 8 + 4];
            float ar[8] = { av0.x, av0.y, av0.z, av0.w, av1.x, av1.y, av1.z, av1.w };
            float wr[4] = { wv.x, wv.y, wv.z, wv.w };
#pragma unroll
            for (int i = 0; i < 8; i++)
#pragma unroll
                for (int j = 0; j < 4; j++)
                    acc[i][j] = fmaf(ar[i], wr[j], acc[i][j]);
        }
        __syncthreads();
    }

    float s[4] = { 0, 0, 0, 0 }, q[4] = { 0, 0, 0, 0 };
#pragma unroll
    for (int i = 0; i < 8; i++) {
        int row = r0 + ty * 8 + i;
        if (row < NN) {
            float4 o = { acc[i][0], acc[i][1], acc[i][2], acc[i][3] };
            *(float4*)&out[row * HD + tx * 4] = o;
#pragma unroll
            for (int j = 0; j < 4; j++) {
                s[j] += acc[i][j];
                q[j] = fmaf(acc[i][j], acc[i][j], q[j]);
            }
        }
    }
    float* ssum = smem;          // [8][128]
    float* ssq  = smem + 1024;   // [8][128]
#pragma unroll
    for (int j = 0; j < 4; j++) {
        ssum[ty * 128 + tx * 4 + j] = s[j];
        ssq[ty * 128 + tx * 4 + j]  = q[j];
    }
    __syncthreads();
    if (tid < 128) {
        float ss = 0.f, qq = 0.f;
#pragma unroll
        for (int i = 0; i < 8; i++) {
            ss += ssum[i * 128 + tid];
            qq += ssq[i * 128 + tid];
        }
        atomicAdd(&colsum[tid], ss);
        atomicAdd(&colsq[tid], qq);
    }
}

// ---------- BN finalize ----------
__global__ void k_bnfin(const float* __restrict__ colsum, const float* __restrict__ colsq,
                        const float* __restrict__ gamma, const float* __restrict__ beta,
                        float* __restrict__ scale, float* __restrict__ shift) {
    int c = threadIdx.x;
    float mu  = colsum[c] * (1.0f / NN);
    float var = colsq[c] * (1.0f / NN) - mu * mu;
    float a = gamma[c] * rsqrtf(var + BN_EPS);
    scale[c] = a;
    shift[c] = beta[c] - a * mu;
}

// ---------- post: h = relu(scale*u+shift) OR pool ----------
template <bool WRITE_H>
__global__ void k_post(const float* __restrict__ u, const float* __restrict__ scale,
                       const float* __restrict__ shift, float* __restrict__ h,
                       const int* __restrict__ batch, float* __restrict__ pooled,
                       float* __restrict__ cnt) {
    int i = blockIdx.x * blockDim.x + threadIdx.x;   // NN*32
    if (i >= NN * (HD / 4)) return;
    int n  = i >> 5;
    int c4 = (i & 31) * 4;
    float4 uv = *(const float4*)&u[n * HD + c4];
    float4 sc = *(const float4*)&scale[c4];
    float4 sh = *(const float4*)&shift[c4];
    float4 hv;
    hv.x = fmaxf(fmaf(sc.x, uv.x, sh.x), 0.f);
    hv.y = fmaxf(fmaf(sc.y, uv.y, sh.y), 0.f);
    hv.z = fmaxf(fmaf(sc.z, uv.z, sh.z), 0.f);
    hv.w = fmaxf(fmaf(sc.w, uv.w, sh.w), 0.f);
    if (WRITE_H) {
        *(float4*)&h[n * HD + c4] = hv;
    } else {
        int g = batch[n];
        float* pp = &pooled[g * HD + c4];
        atomicAdd(pp + 0, hv.x);
        atomicAdd(pp + 1, hv.y);
        atomicAdd(pp + 2, hv.z);
        atomicAdd(pp + 3, hv.w);
        if (c4 == 0) atomicAdd(&cnt[g], 1.0f);
    }
}

// ---------- classifier ----------
__global__ void k_cls(const float* __restrict__ pooled, const float* __restrict__ cnt,
                      const float* __restrict__ Wc, const float* __restrict__ bc,
                      float* __restrict__ out) {
    int t = threadIdx.x;          // 256 threads = 128 graphs x 2 classes
    int g = t >> 1, c = t & 1;
    float inv = 1.0f / fmaxf(cnt[g], 1.0f);
    float acc = bc[c];
    for (int k = 0; k < HD; k++)
        acc = fmaf(pooled[g * HD + k] * inv, Wc[k * NC + c], acc);
    out[g * NC + c] = acc;
}

extern "C" void kernel_launch(void* const* d_in, const int* in_sizes, int n_in,
                              void* d_out, int out_size, void* d_ws, size_t ws_size,
                              hipStream_t stream) {
    const float* x      = (const float*)d_in[0];
    const int*   ei     = (const int*)d_in[1];
    const int*   batch  = (const int*)d_in[2];
    const float* enc_W  = (const float*)d_in[3];
    const float* enc_b  = (const float*)d_in[4];
    const float* W1     = (const float*)d_in[5];
    // d_in[6] = b1 (cancels in BN), d_in[10] = b2 (cancels in BN)
    const float* g1     = (const float*)d_in[7];
    const float* be1    = (const float*)d_in[8];
    const float* W2     = (const float*)d_in[9];
    const float* eps_g  = (const float*)d_in[11];
    const float* bn_g   = (const float*)d_in[12];
    const float* bn_b   = (const float*)d_in[13];
    const float* cls_W  = (const float*)d_in[14];
    const float* cls_b  = (const float*)d_in[15];
    float* out = (float*)d_out;

    float* ws     = (float*)d_ws;
    float* h      = ws;                    // NN*HD
    float* z      = h + NN * HD;           // NN*HD
    float* t      = z + NN * HD;           // NN*HD
    float* stats  = t + NN * HD;           // 6*256
    float* scsh   = stats + 6 * 256;       // 6*256
    float* pooled = scsh + 6 * 256;        // NG*HD
    float* cnt    = pooled + NG * HD;      // NG
    int*   counts  = (int*)(cnt + NG);     // NN (also cursor)
    int*   row_ptr = counts + NN;          // NN+1
    int*   csr_src = row_ptr + NN + 1;     // NE

    hipMemsetAsync(stats, 0, 6 * 256 * sizeof(float), stream);
    hipMemsetAsync(pooled, 0, (NG * HD + NG) * sizeof(float), stream);
    hipMemsetAsync(counts, 0, NN * sizeof(int), stream);

    dim3 b256(256);
    const int nwork = NN * (HD / 4);         // 640000
    const int gemm_blocks = (NN + 63) / 64;  // 313

    // CSR build (by destination), once per call
    k_hist<<<(NE + 255) / 256, b256, 0, stream>>>(ei, counts);
    k_scan<<<1, 1024, 0, stream>>>(counts, row_ptr, counts /*cursor reuse*/);
    k_fill<<<(NE + 255) / 256, b256, 0, stream>>>(ei, counts, csr_src);

    k_enc<<<(nwork + 255) / 256, b256, 0, stream>>>(x, enc_W, enc_b, h);

    for (int l = 0; l < NL; l++) {
        int u1 = l * 2, u2 = l * 2 + 1;
        k_aggr<<<(nwork + 255) / 256, b256, 0, stream>>>(row_ptr, csr_src, h, eps_g, l, z);
        k_gemm<false><<<gemm_blocks, b256, 0, stream>>>(
            z, W1 + l * HD * HD, nullptr, nullptr, t,
            stats + u1 * 256, stats + u1 * 256 + 128);
        k_bnfin<<<1, 128, 0, stream>>>(stats + u1 * 256, stats + u1 * 256 + 128,
                                       g1 + l * HD, be1 + l * HD,
                                       scsh + u1 * 256, scsh + u1 * 256 + 128);
        k_gemm<true><<<gemm_blocks, b256, 0, stream>>>(
            t, W2 + l * HD * HD, scsh + u1 * 256, scsh + u1 * 256 + 128, z,
            stats + u2 * 256, stats + u2 * 256 + 128);
        k_bnfin<<<1, 128, 0, stream>>>(stats + u2 * 256, stats + u2 * 256 + 128,
                                       bn_g + l * HD, bn_b + l * HD,
                                       scsh + u2 * 256, scsh + u2 * 256 + 128);
        if (l < NL - 1) {
            k_post<true><<<(nwork + 255) / 256, b256, 0, stream>>>(
                z, scsh + u2 * 256, scsh + u2 * 256 + 128, h, nullptr, nullptr, nullptr);
        } else {
            k_post<false><<<(nwork + 255) / 256, b256, 0, stream>>>(
                z, scsh + u2 * 256, scsh + u2 * 256 + 128, nullptr, batch, pooled, cnt);
        }
    }
    k_cls<<<1, 256, 0, stream>>>(pooled, cnt, cls_W, cls_b, out);
}

// Round 3
// 546.364 us; speedup vs baseline: 6.5965x; 1.1124x over previous
//
#include <hip/hip_runtime.h>

#define NN 20000
#define NE 640000
#define HD 128
#define NL 3
#define NG 128
#define NC 2
#define BN_EPS 1e-5f

// ---------- CSR build: histogram of dst ----------
__global__ void k_hist(const int* __restrict__ ei, int* __restrict__ counts) {
    int e = blockIdx.x * blockDim.x + threadIdx.x;
    if (e >= NE) return;
    atomicAdd(&counts[ei[NE + e]], 1);
}

// ---------- CSR build: exclusive scan of counts -> row_ptr, cursor ----------
__global__ __launch_bounds__(1024) void k_scan(const int* __restrict__ counts,
                                               int* __restrict__ row_ptr,
                                               int* __restrict__ cursor) {
    __shared__ int sdata[1024];
    __shared__ int carry;
    int tid = threadIdx.x;
    if (tid == 0) carry = 0;
    __syncthreads();
    for (int base = 0; base < NN; base += 1024) {
        int i = base + tid;
        int v = (i < NN) ? counts[i] : 0;
        sdata[tid] = v;
        __syncthreads();
        for (int off = 1; off < 1024; off <<= 1) {
            int t = (tid >= off) ? sdata[tid - off] : 0;
            __syncthreads();
            sdata[tid] += t;
            __syncthreads();
        }
        int carry_local = carry;
        int excl = sdata[tid] - v;
        if (i < NN) {
            row_ptr[i] = carry_local + excl;
            cursor[i]  = carry_local + excl;
        }
        __syncthreads();
        if (tid == 0) carry = carry_local + sdata[1023];
        __syncthreads();
    }
    if (tid == 0) row_ptr[NN] = NE;
}

// ---------- CSR build: fill source lists ----------
__global__ void k_fill(const int* __restrict__ ei, int* __restrict__ cursor,
                       int* __restrict__ csr_src) {
    int e = blockIdx.x * blockDim.x + threadIdx.x;
    if (e >= NE) return;
    int pos = atomicAdd(&cursor[ei[NE + e]], 1);
    csr_src[pos] = ei[e];
}

// ---------- encoder: h = x*enc_W + enc_b ----------
__global__ void k_enc(const float* __restrict__ x, const float* __restrict__ W,
                      const float* __restrict__ b, float* __restrict__ h) {
    int i = blockIdx.x * blockDim.x + threadIdx.x;   // over NN*32 float4 slots
    if (i >= NN * (HD / 4)) return;
    int n  = i >> 5;
    int c4 = (i & 31) * 4;
    float xv = x[n];
    float4 w  = *(const float4*)&W[c4];
    float4 bb = *(const float4*)&b[c4];
    float4 hv;
    hv.x = fmaf(xv, w.x, bb.x);
    hv.y = fmaf(xv, w.y, bb.y);
    hv.z = fmaf(xv, w.z, bb.z);
    hv.w = fmaf(xv, w.w, bb.w);
    *(float4*)&h[n * HD + c4] = hv;
}

// ---------- aggregation (gather) ----------
// APPLY=false: z[n] = (1+eps)*u[n]            + sum_{s} u[s]
// APPLY=true:  z[n] = (1+eps)*f(u[n])         + sum_{s} f(u[s]),
//              f(v) = relu(scale*v + shift)   (fused inter-layer BN+ReLU)
template <bool APPLY>
__global__ void k_aggr(const int* __restrict__ row_ptr, const int* __restrict__ csr_src,
                       const float* __restrict__ u, const float* __restrict__ scale,
                       const float* __restrict__ shift, const float* __restrict__ eps_gin,
                       int l, float* __restrict__ z) {
    int i = blockIdx.x * blockDim.x + threadIdx.x;   // NN*32
    if (i >= NN * (HD / 4)) return;
    int n  = i >> 5;
    int c4 = (i & 31) * 4;
    float e = 1.0f + eps_gin[l];
    float4 sc = { 0, 0, 0, 0 }, sh = { 0, 0, 0, 0 };
    if (APPLY) {
        sc = *(const float4*)&scale[c4];
        sh = *(const float4*)&shift[c4];
    }
    float4 hv = *(const float4*)&u[n * HD + c4];
    if (APPLY) {
        hv.x = fmaxf(fmaf(sc.x, hv.x, sh.x), 0.f);
        hv.y = fmaxf(fmaf(sc.y, hv.y, sh.y), 0.f);
        hv.z = fmaxf(fmaf(sc.z, hv.z, sh.z), 0.f);
        hv.w = fmaxf(fmaf(sc.w, hv.w, sh.w), 0.f);
    }
    float4 acc = { e * hv.x, e * hv.y, e * hv.z, e * hv.w };
    int p   = row_ptr[n];
    int end = row_ptr[n + 1];
    for (; p < end; p++) {
        int s0 = csr_src[p];
        float4 v = *(const float4*)&u[s0 * HD + c4];
        if (APPLY) {
            v.x = fmaxf(fmaf(sc.x, v.x, sh.x), 0.f);
            v.y = fmaxf(fmaf(sc.y, v.y, sh.y), 0.f);
            v.z = fmaxf(fmaf(sc.z, v.z, sh.z), 0.f);
            v.w = fmaxf(fmaf(sc.w, v.w, sh.w), 0.f);
        }
        acc.x += v.x; acc.y += v.y; acc.z += v.z; acc.w += v.w;
    }
    *(float4*)&z[n * HD + c4] = acc;
}

// ---------- GEMM: out = f(A) @ W, plus per-column sum/sumsq stats ----------
// f(A) = A (BNRELU=false) or relu(scale[k]*A + shift[k]) (BNRELU=true).
// Linear biases skipped: they cancel in the following BN.
template <bool BNRELU>
__global__ __launch_bounds__(256) void k_gemm(
    const float* __restrict__ A, const float* __restrict__ W,
    const float* __restrict__ scale, const float* __restrict__ shift,
    float* __restrict__ out, float* __restrict__ colsum, float* __restrict__ colsq) {
    __shared__ __align__(16) float smem[32 * 64 + 32 * 128];  // 24 KB
    float* As = smem;          // [k][row]  32 x 64 (transposed)
    float* Ws = smem + 2048;   // [k][col]  32 x 128

    int tid = threadIdx.x;
    int tx = tid & 31;
    int ty = tid >> 5;
    int r0 = blockIdx.x * 64;

    float acc[8][4];
#pragma unroll
    for (int i = 0; i < 8; i++)
#pragma unroll
        for (int j = 0; j < 4; j++) acc[i][j] = 0.0f;

    for (int k0 = 0; k0 < HD; k0 += 32) {
#pragma unroll
        for (int i = 0; i < 4; i++) {
            int f = tid + i * 256;
            int k = f >> 5;
            int c = (f & 31) * 4;
            *(float4*)&Ws[k * 128 + c] = *(const float4*)&W[(k0 + k) * HD + c];
        }
#pragma unroll
        for (int i = 0; i < 2; i++) {
            int f = tid + i * 256;
            int r = f >> 3;
            int kq = (f & 7) * 4;
            int row = r0 + r;
            float4 v = { 0.f, 0.f, 0.f, 0.f };
            if (row < NN) v = *(const float4*)&A[row * HD + k0 + kq];
            if (BNRELU) {
                v.x = fmaxf(fmaf(scale[k0 + kq + 0], v.x, shift[k0 + kq + 0]), 0.f);
                v.y = fmaxf(fmaf(scale[k0 + kq + 1], v.y, shift[k0 + kq + 1]), 0.f);
                v.z = fmaxf(fmaf(scale[k0 + kq + 2], v.z, shift[k0 + kq + 2]), 0.f);
                v.w = fmaxf(fmaf(scale[k0 + kq + 3], v.w, shift[k0 + kq + 3]), 0.f);
            }
            As[(kq + 0) * 64 + r] = v.x;
            As[(kq + 1) * 64 + r] = v.y;
            As[(kq + 2) * 64 + r] = v.z;
            As[(kq + 3) * 64 + r] = v.w;
        }
        __syncthreads();
#pragma unroll
        for (int k = 0; k < 32; k++) {
            float4 wv  = *(float4*)&Ws[k * 128 + tx * 4];
            float4 av0 = *(float4*)&As[k * 64 + ty * 8];
            float4 av1 = *(float4*)&As[k * 64 + ty * 8 + 4];
            float ar[8] = { av0.x, av0.y, av0.z, av0.w, av1.x, av1.y, av1.z, av1.w };
            float wr[4] = { wv.x, wv.y, wv.z, wv.w };
#pragma unroll
            for (int i = 0; i < 8; i++)
#pragma unroll
                for (int j = 0; j < 4; j++)
                    acc[i][j] = fmaf(ar[i], wr[j], acc[i][j]);
        }
        __syncthreads();
    }

    float s[4] = { 0, 0, 0, 0 }, q[4] = { 0, 0, 0, 0 };
#pragma unroll
    for (int i = 0; i < 8; i++) {
        int row = r0 + ty * 8 + i;
        if (row < NN) {
            float4 o = { acc[i][0], acc[i][1], acc[i][2], acc[i][3] };
            *(float4*)&out[row * HD + tx * 4] = o;
#pragma unroll
            for (int j = 0; j < 4; j++) {
                s[j] += acc[i][j];
                q[j] = fmaf(acc[i][j], acc[i][j], q[j]);
            }
        }
    }
    float* ssum = smem;          // [8][128]
    float* ssq  = smem + 1024;   // [8][128]
#pragma unroll
    for (int j = 0; j < 4; j++) {
        ssum[ty * 128 + tx * 4 + j] = s[j];
        ssq[ty * 128 + tx * 4 + j]  = q[j];
    }
    __syncthreads();
    if (tid < 128) {
        float ss = 0.f, qq = 0.f;
#pragma unroll
        for (int i = 0; i < 8; i++) {
            ss += ssum[i * 128 + tid];
            qq += ssq[i * 128 + tid];
        }
        atomicAdd(&colsum[tid], ss);
        atomicAdd(&colsq[tid], qq);
    }
}

// ---------- BN finalize ----------
__global__ void k_bnfin(const float* __restrict__ colsum, const float* __restrict__ colsq,
                        const float* __restrict__ gamma, const float* __restrict__ beta,
                        float* __restrict__ scale, float* __restrict__ shift) {
    int c = threadIdx.x;
    float mu  = colsum[c] * (1.0f / NN);
    float var = colsq[c] * (1.0f / NN) - mu * mu;
    float a = gamma[c] * rsqrtf(var + BN_EPS);
    scale[c] = a;
    shift[c] = beta[c] - a * mu;
}

// ---------- pool + classifier: one block per graph, no atomics ----------
// batch is sorted: graph g's nodes are contiguous. Binary-search the range,
// reduce relu(scale*u+shift), mean, then apply the 128x2 classifier.
__global__ __launch_bounds__(256) void k_pool(
    const float* __restrict__ u, const float* __restrict__ scale,
    const float* __restrict__ shift, const int* __restrict__ batch,
    const float* __restrict__ Wc, const float* __restrict__ bc,
    float* __restrict__ out) {
    __shared__ float part[2][HD];
    __shared__ float pooled[HD];
    __shared__ int range[2];
    int g = blockIdx.x;
    int tid = threadIdx.x;
    if (tid < 2) {
        int target = g + tid;
        int lo = 0, hi = NN;
        while (lo < hi) {
            int mid = (lo + hi) >> 1;
            if (batch[mid] < target) lo = mid + 1; else hi = mid;
        }
        range[tid] = lo;
    }
    __syncthreads();
    int start = range[0], end = range[1];
    int c    = tid & (HD - 1);
    int half = tid >> 7;
    float sc = scale[c], sh = shift[c];
    float acc = 0.f;
    for (int n = start + half; n < end; n += 2)
        acc += fmaxf(fmaf(sc, u[n * HD + c], sh), 0.f);
    part[half][c] = acc;
    __syncthreads();
    if (tid < HD) {
        float inv = 1.0f / fmaxf((float)(end - start), 1.0f);
        pooled[tid] = (part[0][tid] + part[1][tid]) * inv;
    }
    __syncthreads();
    if (tid < NC) {
        float a = bc[tid];
        for (int k = 0; k < HD; k++)
            a = fmaf(pooled[k], Wc[k * NC + tid], a);
        out[g * NC + tid] = a;
    }
}

extern "C" void kernel_launch(void* const* d_in, const int* in_sizes, int n_in,
                              void* d_out, int out_size, void* d_ws, size_t ws_size,
                              hipStream_t stream) {
    const float* x      = (const float*)d_in[0];
    const int*   ei     = (const int*)d_in[1];
    const int*   batch  = (const int*)d_in[2];
    const float* enc_W  = (const float*)d_in[3];
    const float* enc_b  = (const float*)d_in[4];
    const float* W1     = (const float*)d_in[5];
    // d_in[6] = b1 (cancels in BN), d_in[10] = b2 (cancels in BN)
    const float* g1     = (const float*)d_in[7];
    const float* be1    = (const float*)d_in[8];
    const float* W2     = (const float*)d_in[9];
    const float* eps_g  = (const float*)d_in[11];
    const float* bn_g   = (const float*)d_in[12];
    const float* bn_b   = (const float*)d_in[13];
    const float* cls_W  = (const float*)d_in[14];
    const float* cls_b  = (const float*)d_in[15];
    float* out = (float*)d_out;

    float* ws      = (float*)d_ws;
    float* bufA    = ws;                   // NN*HD  (enc output; rotates)
    float* bufB    = bufA + NN * HD;       // NN*HD
    float* bufC    = bufB + NN * HD;       // NN*HD  (gemm1 output)
    float* stats   = bufC + NN * HD;       // 6*256
    float* scsh    = stats + 6 * 256;      // 6*256
    int*   counts  = (int*)(scsh + 6 * 256); // NN (also cursor)
    int*   row_ptr = counts + NN;          // NN+1
    int*   csr_src = row_ptr + NN + 1;     // NE

    hipMemsetAsync(stats, 0, 6 * 256 * sizeof(float), stream);
    hipMemsetAsync(counts, 0, NN * sizeof(int), stream);

    dim3 b256(256);
    const int nwork = NN * (HD / 4);         // 640000
    const int gemm_blocks = (NN + 63) / 64;  // 313

    // CSR build (by destination)
    k_hist<<<(NE + 255) / 256, b256, 0, stream>>>(ei, counts);
    k_scan<<<1, 1024, 0, stream>>>(counts, row_ptr, counts /*cursor*/);
    k_fill<<<(NE + 255) / 256, b256, 0, stream>>>(ei, counts, csr_src);

    k_enc<<<(nwork + 255) / 256, b256, 0, stream>>>(x, enc_W, enc_b, bufA);

    float* in = bufA;
    for (int l = 0; l < NL; l++) {
        int u1 = l * 2, u2 = l * 2 + 1;
        float* X = (l % 2 == 0) ? bufB : bufA;   // aggr out, then gemm2 out
        if (l == 0) {
            k_aggr<false><<<(nwork + 255) / 256, b256, 0, stream>>>(
                row_ptr, csr_src, in, nullptr, nullptr, eps_g, l, X);
        } else {
            int up = (l - 1) * 2 + 1;            // previous outer BN
            k_aggr<true><<<(nwork + 255) / 256, b256, 0, stream>>>(
                row_ptr, csr_src, in, scsh + up * 256, scsh + up * 256 + 128,
                eps_g, l, X);
        }
        k_gemm<false><<<gemm_blocks, b256, 0, stream>>>(
            X, W1 + l * HD * HD, nullptr, nullptr, bufC,
            stats + u1 * 256, stats + u1 * 256 + 128);
        k_bnfin<<<1, 128, 0, stream>>>(stats + u1 * 256, stats + u1 * 256 + 128,
                                       g1 + l * HD, be1 + l * HD,
                                       scsh + u1 * 256, scsh + u1 * 256 + 128);
        k_gemm<true><<<gemm_blocks, b256, 0, stream>>>(
            bufC, W2 + l * HD * HD, scsh + u1 * 256, scsh + u1 * 256 + 128, X,
            stats + u2 * 256, stats + u2 * 256 + 128);
        k_bnfin<<<1, 128, 0, stream>>>(stats + u2 * 256, stats + u2 * 256 + 128,
                                       bn_g + l * HD, bn_b + l * HD,
                                       scsh + u2 * 256, scsh + u2 * 256 + 128);
        in = X;
    }
    // in == buffer holding u of layer 2 (pre outer-BN); unit 5 scale/shift
    k_pool<<<NG, b256, 0, stream>>>(in, scsh + 5 * 256, scsh + 5 * 256 + 128,
                                    batch, cls_W, cls_b, out);
}

// Round 5
// 464.353 us; speedup vs baseline: 7.7616x; 1.1766x over previous
//
#include <hip/hip_runtime.h>

#define NN 20000
#define NE 640000
#define HD 128
#define NL 3
#define NG 128
#define NC 2
#define BN_EPS 1e-5f

typedef __attribute__((ext_vector_type(8))) short bf16x8;
typedef __attribute__((ext_vector_type(4))) float f32x4;

__device__ __forceinline__ float bf2f(unsigned short u) {
    union { unsigned int i; float f; } x; x.i = ((unsigned int)u) << 16; return x.f;
}
__device__ __forceinline__ unsigned short f2bf(float f) {
    union { float f; unsigned int i; } x; x.f = f;
    unsigned int r = x.i + 0x7fffu + ((x.i >> 16) & 1u);
    return (unsigned short)(r >> 16);
}

// ---------- weight prep: split-bf16 transpose ----------
// Whi[mat][n][k] = bf16(W[mat][k][n]); Wlo[mat][n][k] = bf16(W[k][n] - Whi)
// mat = 2l + which; Wlo stored at offset (6+mat).
__global__ void k_prep(const float* __restrict__ W1, const float* __restrict__ W2,
                       unsigned short* __restrict__ Wt) {
    int t = blockIdx.x * blockDim.x + threadIdx.x;   // 6*2048 threads, 8 outputs each
    if (t >= 6 * 2048) return;
    int mat = t >> 11;
    int rem = t & 2047;
    int n  = rem >> 4;
    int k0 = (rem & 15) * 8;
    int l  = mat >> 1;
    const float* src = (mat & 1) ? (W2 + l * HD * HD) : (W1 + l * HD * HD);
    unsigned short* dhi = Wt + mat * HD * HD;
    unsigned short* dlo = Wt + (6 + mat) * HD * HD;
    union { bf16x8 v; unsigned short u[8]; } hi, lo;
#pragma unroll
    for (int j = 0; j < 8; j++) {
        float w = src[(k0 + j) * HD + n];
        hi.u[j] = f2bf(w);
        lo.u[j] = f2bf(w - bf2f(hi.u[j]));
    }
    *(bf16x8*)&dhi[n * HD + k0] = hi.v;
    *(bf16x8*)&dlo[n * HD + k0] = lo.v;
}

// ---------- CSR build ----------
__global__ void k_hist(const int* __restrict__ ei, int* __restrict__ counts) {
    int e = blockIdx.x * blockDim.x + threadIdx.x;
    if (e >= NE) return;
    atomicAdd(&counts[ei[NE + e]], 1);
}

__global__ __launch_bounds__(1024) void k_scan(const int* __restrict__ counts,
                                               int* __restrict__ row_ptr,
                                               int* __restrict__ cursor) {
    __shared__ int sdata[1024];
    int tid = threadIdx.x;
    int base = tid * 20;
    int loc[20];
    int run = 0;
#pragma unroll
    for (int j = 0; j < 20; j++) {
        int i = base + j;
        int v = (i < NN) ? counts[i] : 0;
        loc[j] = run;
        run += v;
    }
    sdata[tid] = run;
    __syncthreads();
    for (int off = 1; off < 1024; off <<= 1) {
        int t = (tid >= off) ? sdata[tid - off] : 0;
        __syncthreads();
        sdata[tid] += t;
        __syncthreads();
    }
    int excl = sdata[tid] - run;
#pragma unroll
    for (int j = 0; j < 20; j++) {
        int i = base + j;
        if (i < NN) {
            int o = excl + loc[j];
            row_ptr[i] = o;
            cursor[i]  = o;
        }
    }
    if (tid == 1023) row_ptr[NN] = NE;
}

__global__ void k_fill(const int* __restrict__ ei, int* __restrict__ cursor,
                       int* __restrict__ csr_src) {
    int e = blockIdx.x * blockDim.x + threadIdx.x;
    if (e >= NE) return;
    int pos = atomicAdd(&cursor[ei[NE + e]], 1);
    csr_src[pos] = ei[e];
}

// ---------- encoder: h = x*enc_W + enc_b (fp32) ----------
__global__ void k_enc(const float* __restrict__ x, const float* __restrict__ W,
                      const float* __restrict__ b, float* __restrict__ h) {
    int i = blockIdx.x * blockDim.x + threadIdx.x;   // NN*32 float4 slots
    if (i >= NN * 32) return;
    int n  = i >> 5;
    int c4 = (i & 31) * 4;
    float xv = x[n];
    float4 w  = *(const float4*)&W[c4];
    float4 bb = *(const float4*)&b[c4];
    float4 hv;
    hv.x = fmaf(xv, w.x, bb.x);
    hv.y = fmaf(xv, w.y, bb.y);
    hv.z = fmaf(xv, w.z, bb.z);
    hv.w = fmaf(xv, w.w, bb.w);
    *(float4*)&h[n * HD + c4] = hv;
}

// ---------- aggregation (fp32 gather) ----------
// APPLY: f(v) = relu(sc*v+sh), BN params computed inline from stats.
template <bool APPLY>
__global__ void k_aggr(const int* __restrict__ row_ptr, const int* __restrict__ csr_src,
                       const float* __restrict__ u,
                       const float* __restrict__ pcolsum, const float* __restrict__ pcolsq,
                       const float* __restrict__ gamma, const float* __restrict__ beta,
                       const float* __restrict__ eps_gin, int l,
                       float* __restrict__ z) {
    int i = blockIdx.x * blockDim.x + threadIdx.x;   // NN*32
    if (i >= NN * 32) return;
    int n  = i >> 5;
    int c4 = (i & 31) * 4;
    float e = 1.0f + eps_gin[l];
    float4 sc = { 0, 0, 0, 0 }, sh = { 0, 0, 0, 0 };
    if (APPLY) {
#pragma unroll
        for (int j = 0; j < 4; j++) {
            float mu  = pcolsum[c4 + j] * (1.0f / NN);
            float var = pcolsq[c4 + j] * (1.0f / NN) - mu * mu;
            float a = gamma[c4 + j] * rsqrtf(var + BN_EPS);
            ((float*)&sc)[j] = a;
            ((float*)&sh)[j] = beta[c4 + j] - a * mu;
        }
    }
    float4 hv = *(const float4*)&u[n * HD + c4];
    if (APPLY) {
        hv.x = fmaxf(fmaf(sc.x, hv.x, sh.x), 0.f);
        hv.y = fmaxf(fmaf(sc.y, hv.y, sh.y), 0.f);
        hv.z = fmaxf(fmaf(sc.z, hv.z, sh.z), 0.f);
        hv.w = fmaxf(fmaf(sc.w, hv.w, sh.w), 0.f);
    }
    float4 acc = { e * hv.x, e * hv.y, e * hv.z, e * hv.w };
    int p = row_ptr[n], end = row_ptr[n + 1];
    for (; p + 3 < end; p += 4) {
        int s0 = csr_src[p], s1 = csr_src[p + 1], s2 = csr_src[p + 2], s3 = csr_src[p + 3];
        float4 v0 = *(const float4*)&u[s0 * HD + c4];
        float4 v1 = *(const float4*)&u[s1 * HD + c4];
        float4 v2 = *(const float4*)&u[s2 * HD + c4];
        float4 v3 = *(const float4*)&u[s3 * HD + c4];
        if (APPLY) {
            v0.x = fmaxf(fmaf(sc.x, v0.x, sh.x), 0.f); v0.y = fmaxf(fmaf(sc.y, v0.y, sh.y), 0.f);
            v0.z = fmaxf(fmaf(sc.z, v0.z, sh.z), 0.f); v0.w = fmaxf(fmaf(sc.w, v0.w, sh.w), 0.f);
            v1.x = fmaxf(fmaf(sc.x, v1.x, sh.x), 0.f); v1.y = fmaxf(fmaf(sc.y, v1.y, sh.y), 0.f);
            v1.z = fmaxf(fmaf(sc.z, v1.z, sh.z), 0.f); v1.w = fmaxf(fmaf(sc.w, v1.w, sh.w), 0.f);
            v2.x = fmaxf(fmaf(sc.x, v2.x, sh.x), 0.f); v2.y = fmaxf(fmaf(sc.y, v2.y, sh.y), 0.f);
            v2.z = fmaxf(fmaf(sc.z, v2.z, sh.z), 0.f); v2.w = fmaxf(fmaf(sc.w, v2.w, sh.w), 0.f);
            v3.x = fmaxf(fmaf(sc.x, v3.x, sh.x), 0.f); v3.y = fmaxf(fmaf(sc.y, v3.y, sh.y), 0.f);
            v3.z = fmaxf(fmaf(sc.z, v3.z, sh.z), 0.f); v3.w = fmaxf(fmaf(sc.w, v3.w, sh.w), 0.f);
        }
        acc.x += (v0.x + v1.x) + (v2.x + v3.x);
        acc.y += (v0.y + v1.y) + (v2.y + v3.y);
        acc.z += (v0.z + v1.z) + (v2.z + v3.z);
        acc.w += (v0.w + v1.w) + (v2.w + v3.w);
    }
    for (; p < end; p++) {
        int s0 = csr_src[p];
        float4 v0 = *(const float4*)&u[s0 * HD + c4];
        if (APPLY) {
            v0.x = fmaxf(fmaf(sc.x, v0.x, sh.x), 0.f); v0.y = fmaxf(fmaf(sc.y, v0.y, sh.y), 0.f);
            v0.z = fmaxf(fmaf(sc.z, v0.z, sh.z), 0.f); v0.w = fmaxf(fmaf(sc.w, v0.w, sh.w), 0.f);
        }
        acc.x += v0.x; acc.y += v0.y; acc.z += v0.z; acc.w += v0.w;
    }
    *(float4*)&z[n * HD + c4] = acc;
}

// ---------- split-bf16 MFMA GEMM: out_f32 = f(A_f32) @ W^T ----------
// A and W are decomposed x = hi + lo (bf16 each); product uses
// Ahi*Whi + Ahi*Wlo + Alo*Whi (dropped Alo*Wlo ~ 2^-18) -> fp32-accurate.
// f = identity or inline-BN+ReLU (applied to fp32 A before splitting).
// 64 rows x 128 cols per block, 4 waves each owning a 32-col strip.
// MFMA 16x16x32 bf16: A[m=lane&15][k=quad*8+j]; C/D col=lane&15, row=quad*4+reg.
template <bool BNRELU>
__global__ __launch_bounds__(256) void k_gemm(
    const float* __restrict__ A, const unsigned short* __restrict__ Whi,
    const unsigned short* __restrict__ Wlo,
    const float* __restrict__ pcolsum, const float* __restrict__ pcolsq,
    const float* __restrict__ gamma, const float* __restrict__ beta,
    float* __restrict__ out,
    float* __restrict__ colsum, float* __restrict__ colsq) {
    int tid  = threadIdx.x;
    int wave = tid >> 6, lane = tid & 63;
    int quad = lane >> 4, l16 = lane & 15;
    int r0   = blockIdx.x * 64;
    int n0w  = wave * 32;

    bf16x8 bhi[2][4], blo[2][4];
#pragma unroll
    for (int nt = 0; nt < 2; nt++) {
        int n = n0w + nt * 16 + l16;
#pragma unroll
        for (int kq = 0; kq < 4; kq++) {
            int k = kq * 32 + quad * 8;
            bhi[nt][kq] = *(const bf16x8*)&Whi[n * HD + k];
            blo[nt][kq] = *(const bf16x8*)&Wlo[n * HD + k];
        }
    }
    float sc[4][8], sh[4][8];
    if (BNRELU) {
#pragma unroll
        for (int kq = 0; kq < 4; kq++) {
            int k = kq * 32 + quad * 8;
#pragma unroll
            for (int j = 0; j < 8; j++) {
                float mu  = pcolsum[k + j] * (1.0f / NN);
                float var = pcolsq[k + j] * (1.0f / NN) - mu * mu;
                float a = gamma[k + j] * rsqrtf(var + BN_EPS);
                sc[kq][j] = a;
                sh[kq][j] = beta[k + j] - a * mu;
            }
        }
    }

    f32x4 acc[4][2];
#pragma unroll
    for (int mt = 0; mt < 4; mt++)
#pragma unroll
        for (int nt = 0; nt < 2; nt++)
#pragma unroll
            for (int e = 0; e < 4; e++) acc[mt][nt][e] = 0.f;

#pragma unroll
    for (int mt = 0; mt < 4; mt++) {
        int m = r0 + mt * 16 + l16;
        bf16x8 ahi[4], alo[4];
#pragma unroll
        for (int kq = 0; kq < 4; kq++) {
            int k = kq * 32 + quad * 8;
            float av[8];
            if (m < NN) {
                float4 a0 = *(const float4*)&A[m * HD + k];
                float4 a1 = *(const float4*)&A[m * HD + k + 4];
                av[0] = a0.x; av[1] = a0.y; av[2] = a0.z; av[3] = a0.w;
                av[4] = a1.x; av[5] = a1.y; av[6] = a1.z; av[7] = a1.w;
            } else {
#pragma unroll
                for (int j = 0; j < 8; j++) av[j] = 0.f;
            }
            union { bf16x8 v; unsigned short u[8]; } h8, l8;
#pragma unroll
            for (int j = 0; j < 8; j++) {
                float a = av[j];
                if (BNRELU) a = fmaxf(fmaf(sc[kq][j], a, sh[kq][j]), 0.f);
                h8.u[j] = f2bf(a);
                l8.u[j] = f2bf(a - bf2f(h8.u[j]));
            }
            ahi[kq] = h8.v;
            alo[kq] = l8.v;
        }
#pragma unroll
        for (int nt = 0; nt < 2; nt++)
#pragma unroll
            for (int kq = 0; kq < 4; kq++) {
                acc[mt][nt] = __builtin_amdgcn_mfma_f32_16x16x32_bf16(
                    ahi[kq], bhi[nt][kq], acc[mt][nt], 0, 0, 0);
                acc[mt][nt] = __builtin_amdgcn_mfma_f32_16x16x32_bf16(
                    ahi[kq], blo[nt][kq], acc[mt][nt], 0, 0, 0);
                acc[mt][nt] = __builtin_amdgcn_mfma_f32_16x16x32_bf16(
                    alo[kq], bhi[nt][kq], acc[mt][nt], 0, 0, 0);
            }
    }

    float s[2] = { 0.f, 0.f }, q[2] = { 0.f, 0.f };
#pragma unroll
    for (int mt = 0; mt < 4; mt++) {
        int rbase = r0 + mt * 16 + quad * 4;
#pragma unroll
        for (int rr = 0; rr < 4; rr++) {
            int row = rbase + rr;
            if (row < NN) {
#pragma unroll
                for (int nt = 0; nt < 2; nt++) {
                    float v = acc[mt][nt][rr];
                    out[row * HD + n0w + nt * 16 + l16] = v;
                    s[nt] += v;
                    q[nt] = fmaf(v, v, q[nt]);
                }
            }
        }
    }
#pragma unroll
    for (int nt = 0; nt < 2; nt++) {
        float ss = s[nt], qq = q[nt];
        ss += __shfl_xor(ss, 16); ss += __shfl_xor(ss, 32);
        qq += __shfl_xor(qq, 16); qq += __shfl_xor(qq, 32);
        if (lane < 16) {
            atomicAdd(&colsum[n0w + nt * 16 + lane], ss);
            atomicAdd(&colsq[n0w + nt * 16 + lane], qq);
        }
    }
}

// ---------- pool + classifier: one block per graph, inline BN ----------
__global__ __launch_bounds__(256) void k_pool(
    const float* __restrict__ u,
    const float* __restrict__ pcolsum, const float* __restrict__ pcolsq,
    const float* __restrict__ gamma, const float* __restrict__ beta,
    const int* __restrict__ batch, const float* __restrict__ Wc,
    const float* __restrict__ bc, float* __restrict__ out) {
    __shared__ float part[2][HD];
    __shared__ float pooled[HD];
    __shared__ int range[2];
    int g = blockIdx.x;
    int tid = threadIdx.x;
    if (tid < 2) {
        int target = g + tid;
        int lo = 0, hi = NN;
        while (lo < hi) {
            int mid = (lo + hi) >> 1;
            if (batch[mid] < target) lo = mid + 1; else hi = mid;
        }
        range[tid] = lo;
    }
    __syncthreads();
    int start = range[0], end = range[1];
    int c    = tid & (HD - 1);
    int half = tid >> 7;
    float mu  = pcolsum[c] * (1.0f / NN);
    float var = pcolsq[c] * (1.0f / NN) - mu * mu;
    float sc = gamma[c] * rsqrtf(var + BN_EPS);
    float sh = beta[c] - sc * mu;
    float acc = 0.f;
    for (int n = start + half; n < end; n += 2)
        acc += fmaxf(fmaf(sc, u[n * HD + c], sh), 0.f);
    part[half][c] = acc;
    __syncthreads();
    if (tid < HD) {
        float inv = 1.0f / fmaxf((float)(end - start), 1.0f);
        pooled[tid] = (part[0][tid] + part[1][tid]) * inv;
    }
    __syncthreads();
    if (tid < NC) {
        float a = bc[tid];
        for (int k = 0; k < HD; k++)
            a = fmaf(pooled[k], Wc[k * NC + tid], a);
        out[g * NC + tid] = a;
    }
}

extern "C" void kernel_launch(void* const* d_in, const int* in_sizes, int n_in,
                              void* d_out, int out_size, void* d_ws, size_t ws_size,
                              hipStream_t stream) {
    const float* x      = (const float*)d_in[0];
    const int*   ei     = (const int*)d_in[1];
    const int*   batch  = (const int*)d_in[2];
    const float* enc_W  = (const float*)d_in[3];
    const float* enc_b  = (const float*)d_in[4];
    const float* W1     = (const float*)d_in[5];
    // d_in[6] = b1, d_in[10] = b2: cancel in the following BN (mean shift)
    const float* g1     = (const float*)d_in[7];
    const float* be1    = (const float*)d_in[8];
    const float* W2     = (const float*)d_in[9];
    const float* eps_g  = (const float*)d_in[11];
    const float* bn_g   = (const float*)d_in[12];
    const float* bn_b   = (const float*)d_in[13];
    const float* cls_W  = (const float*)d_in[14];
    const float* cls_b  = (const float*)d_in[15];
    float* out = (float*)d_out;

    float*          stats = (float*)d_ws;                       // 6 x (128 sum + 128 sq)
    unsigned short* Wt    = (unsigned short*)(stats + 6 * 256); // 12 x 128 x 128 bf16 (hi:0-5, lo:6-11)
    float* bufA = (float*)(Wt + 12 * HD * HD);                  // NN*HD fp32
    float* bufB = bufA + NN * HD;
    float* bufC = bufB + NN * HD;
    int* counts  = (int*)(bufC + NN * HD);                      // NN (also cursor)
    int* row_ptr = counts + NN;                                 // NN+1
    int* csr_src = row_ptr + NN + 1;                            // NE

    hipMemsetAsync(stats, 0, 6 * 256 * sizeof(float), stream);
    hipMemsetAsync(counts, 0, NN * sizeof(int), stream);

    dim3 b256(256);
    k_prep<<<(6 * 2048 + 255) / 256, b256, 0, stream>>>(W1, W2, Wt);
    k_hist<<<(NE + 255) / 256, b256, 0, stream>>>(ei, counts);
    k_scan<<<1, 1024, 0, stream>>>(counts, row_ptr, counts /*cursor*/);
    k_fill<<<(NE + 255) / 256, b256, 0, stream>>>(ei, counts, csr_src);
    k_enc<<<(NN * 32 + 255) / 256, b256, 0, stream>>>(x, enc_W, enc_b, bufA);

    const int aggr_blocks = (NN * 32 + 255) / 256;   // 2500
    const int gemm_blocks = (NN + 63) / 64;          // 313

    float* in = bufA;
    for (int l = 0; l < NL; l++) {
        float* st1 = stats + (2 * l) * 256;       // t stats
        float* st2 = stats + (2 * l + 1) * 256;   // u stats
        float* X = (l % 2 == 0) ? bufB : bufA;
        if (l == 0) {
            k_aggr<false><<<aggr_blocks, b256, 0, stream>>>(
                row_ptr, csr_src, in, nullptr, nullptr, nullptr, nullptr,
                eps_g, l, X);
        } else {
            float* stp = stats + (2 * (l - 1) + 1) * 256;
            k_aggr<true><<<aggr_blocks, b256, 0, stream>>>(
                row_ptr, csr_src, in, stp, stp + 128,
                bn_g + (l - 1) * HD, bn_b + (l - 1) * HD, eps_g, l, X);
        }
        k_gemm<false><<<gemm_blocks, b256, 0, stream>>>(
            X, Wt + (2 * l) * HD * HD, Wt + (6 + 2 * l) * HD * HD,
            nullptr, nullptr, nullptr, nullptr, bufC, st1, st1 + 128);
        k_gemm<true><<<gemm_blocks, b256, 0, stream>>>(
            bufC, Wt + (2 * l + 1) * HD * HD, Wt + (6 + 2 * l + 1) * HD * HD,
            st1, st1 + 128, g1 + l * HD, be1 + l * HD, X, st2, st2 + 128);
        in = X;
    }
    float* st5 = stats + 5 * 256;
    k_pool<<<NG, b256, 0, stream>>>(in, st5, st5 + 128,
                                    bn_g + 2 * HD, bn_b + 2 * HD,
                                    batch, cls_W, cls_b, out);
}

// Round 6
// 424.145 us; speedup vs baseline: 8.4974x; 1.0948x over previous
//
#include <hip/hip_runtime.h>

#define NN 20000
#define NE 640000
#define HD 128
#define NL 3
#define NG 128
#define NC 2
#define BN_EPS 1e-5f

typedef __attribute__((ext_vector_type(8))) short bf16x8;
typedef __attribute__((ext_vector_type(4))) float f32x4;

__device__ __forceinline__ float bf2f(unsigned short u) {
    union { unsigned int i; float f; } x; x.i = ((unsigned int)u) << 16; return x.f;
}
__device__ __forceinline__ unsigned short f2bf(float f) {
    union { float f; unsigned int i; } x; x.f = f;
    unsigned int r = x.i + 0x7fffu + ((x.i >> 16) & 1u);
    return (unsigned short)(r >> 16);
}

// ---------- weight prep: split-bf16 transpose ----------
// Whi[mat][n][k] = bf16(W[mat][k][n]); Wlo = bf16(residual); lo at offset 6+mat.
__global__ void k_prep(const float* __restrict__ W1, const float* __restrict__ W2,
                       unsigned short* __restrict__ Wt) {
    int t = blockIdx.x * blockDim.x + threadIdx.x;
    if (t >= 6 * 2048) return;
    int mat = t >> 11;
    int rem = t & 2047;
    int n  = rem >> 4;
    int k0 = (rem & 15) * 8;
    int l  = mat >> 1;
    const float* src = (mat & 1) ? (W2 + l * HD * HD) : (W1 + l * HD * HD);
    unsigned short* dhi = Wt + mat * HD * HD;
    unsigned short* dlo = Wt + (6 + mat) * HD * HD;
    union { bf16x8 v; unsigned short u[8]; } hi, lo;
#pragma unroll
    for (int j = 0; j < 8; j++) {
        float w = src[(k0 + j) * HD + n];
        hi.u[j] = f2bf(w);
        lo.u[j] = f2bf(w - bf2f(hi.u[j]));
    }
    *(bf16x8*)&dhi[n * HD + k0] = hi.v;
    *(bf16x8*)&dlo[n * HD + k0] = lo.v;
}

// ---------- CSR build ----------
__global__ void k_hist(const int* __restrict__ ei, int* __restrict__ counts) {
    int e = blockIdx.x * blockDim.x + threadIdx.x;
    if (e >= NE) return;
    atomicAdd(&counts[ei[NE + e]], 1);
}

__global__ __launch_bounds__(1024) void k_scan(const int* __restrict__ counts,
                                               int* __restrict__ row_ptr,
                                               int* __restrict__ cursor) {
    __shared__ int sdata[1024];
    int tid = threadIdx.x;
    int base = tid * 20;
    int loc[20];
    int run = 0;
#pragma unroll
    for (int j = 0; j < 20; j++) {
        int i = base + j;
        int v = (i < NN) ? counts[i] : 0;
        loc[j] = run;
        run += v;
    }
    sdata[tid] = run;
    __syncthreads();
    for (int off = 1; off < 1024; off <<= 1) {
        int t = (tid >= off) ? sdata[tid - off] : 0;
        __syncthreads();
        sdata[tid] += t;
        __syncthreads();
    }
    int excl = sdata[tid] - run;
#pragma unroll
    for (int j = 0; j < 20; j++) {
        int i = base + j;
        if (i < NN) {
            int o = excl + loc[j];
            row_ptr[i] = o;
            cursor[i]  = o;
        }
    }
    if (tid == 1023) row_ptr[NN] = NE;
}

__global__ void k_fill(const int* __restrict__ ei, int* __restrict__ cursor,
                       int* __restrict__ csr_src) {
    int e = blockIdx.x * blockDim.x + threadIdx.x;
    if (e >= NE) return;
    int pos = atomicAdd(&cursor[ei[NE + e]], 1);
    csr_src[pos] = ei[e];
}

// ---------- encoder: h = x*enc_W + enc_b (fp32) ----------
__global__ void k_enc(const float* __restrict__ x, const float* __restrict__ W,
                      const float* __restrict__ b, float* __restrict__ h) {
    int i = blockIdx.x * blockDim.x + threadIdx.x;
    if (i >= NN * 32) return;
    int n  = i >> 5;
    int c4 = (i & 31) * 4;
    float xv = x[n];
    float4 w  = *(const float4*)&W[c4];
    float4 bb = *(const float4*)&b[c4];
    float4 hv;
    hv.x = fmaf(xv, w.x, bb.x);
    hv.y = fmaf(xv, w.y, bb.y);
    hv.z = fmaf(xv, w.z, bb.z);
    hv.w = fmaf(xv, w.w, bb.w);
    *(float4*)&h[n * HD + c4] = hv;
}

// ---------- aggregation (fp32 gather, 8-deep unroll) ----------
template <bool APPLY>
__global__ void k_aggr(const int* __restrict__ row_ptr, const int* __restrict__ csr_src,
                       const float* __restrict__ u,
                       const float* __restrict__ pcolsum, const float* __restrict__ pcolsq,
                       const float* __restrict__ gamma, const float* __restrict__ beta,
                       const float* __restrict__ eps_gin, int l,
                       float* __restrict__ z) {
    int i = blockIdx.x * blockDim.x + threadIdx.x;   // NN*32
    if (i >= NN * 32) return;
    int n  = i >> 5;
    int c4 = (i & 31) * 4;
    float e = 1.0f + eps_gin[l];
    float4 sc = { 0, 0, 0, 0 }, sh = { 0, 0, 0, 0 };
    if (APPLY) {
#pragma unroll
        for (int j = 0; j < 4; j++) {
            float mu  = pcolsum[c4 + j] * (1.0f / NN);
            float var = pcolsq[c4 + j] * (1.0f / NN) - mu * mu;
            float a = gamma[c4 + j] * rsqrtf(var + BN_EPS);
            ((float*)&sc)[j] = a;
            ((float*)&sh)[j] = beta[c4 + j] - a * mu;
        }
    }
    float4 hv = *(const float4*)&u[n * HD + c4];
    if (APPLY) {
        hv.x = fmaxf(fmaf(sc.x, hv.x, sh.x), 0.f);
        hv.y = fmaxf(fmaf(sc.y, hv.y, sh.y), 0.f);
        hv.z = fmaxf(fmaf(sc.z, hv.z, sh.z), 0.f);
        hv.w = fmaxf(fmaf(sc.w, hv.w, sh.w), 0.f);
    }
    float4 acc = { e * hv.x, e * hv.y, e * hv.z, e * hv.w };
    int p = row_ptr[n], end = row_ptr[n + 1];
    for (; p + 7 < end; p += 8) {
        float4 v[8];
#pragma unroll
        for (int j = 0; j < 8; j++) v[j] = *(const float4*)&u[csr_src[p + j] * HD + c4];
#pragma unroll
        for (int j = 0; j < 8; j++) {
            if (APPLY) {
                v[j].x = fmaxf(fmaf(sc.x, v[j].x, sh.x), 0.f);
                v[j].y = fmaxf(fmaf(sc.y, v[j].y, sh.y), 0.f);
                v[j].z = fmaxf(fmaf(sc.z, v[j].z, sh.z), 0.f);
                v[j].w = fmaxf(fmaf(sc.w, v[j].w, sh.w), 0.f);
            }
            acc.x += v[j].x; acc.y += v[j].y; acc.z += v[j].z; acc.w += v[j].w;
        }
    }
    for (; p < end; p++) {
        float4 v0 = *(const float4*)&u[csr_src[p] * HD + c4];
        if (APPLY) {
            v0.x = fmaxf(fmaf(sc.x, v0.x, sh.x), 0.f); v0.y = fmaxf(fmaf(sc.y, v0.y, sh.y), 0.f);
            v0.z = fmaxf(fmaf(sc.z, v0.z, sh.z), 0.f); v0.w = fmaxf(fmaf(sc.w, v0.w, sh.w), 0.f);
        }
        acc.x += v0.x; acc.y += v0.y; acc.z += v0.z; acc.w += v0.w;
    }
    *(float4*)&z[n * HD + c4] = acc;
}

// ---------- split-bf16 MFMA GEMM, LDS-staged A ----------
// out_f32 = f(A_f32) @ W^T via Ahi*Whi + Ahi*Wlo + Alo*Whi.
// 64 rows x 128 cols per block, 4 waves each own a 32-col strip.
// A staged coalesced (float4), BN+ReLU+split applied once per element during
// staging (each thread owns 4 fixed channels -> sc/sh computed once).
// LDS stride 136 shorts: 16B-aligned ds_read_b128, <=2-way bank aliasing (free).
#define AST 136
template <bool BNRELU>
__global__ __launch_bounds__(256) void k_gemm(
    const float* __restrict__ A, const unsigned short* __restrict__ Whi,
    const unsigned short* __restrict__ Wlo,
    const float* __restrict__ pcolsum, const float* __restrict__ pcolsq,
    const float* __restrict__ gamma, const float* __restrict__ beta,
    float* __restrict__ out,
    float* __restrict__ colsum, float* __restrict__ colsq) {
    __shared__ __align__(16) unsigned short AsH[64 * AST];
    __shared__ __align__(16) unsigned short AsL[64 * AST];
    int tid  = threadIdx.x;
    int wave = tid >> 6, lane = tid & 63;
    int quad = lane >> 4, l16 = lane & 15;
    int r0   = blockIdx.x * 64;
    int n0w  = wave * 32;

    // B fragments (weights), once per block
    bf16x8 bhi[2][4], blo[2][4];
#pragma unroll
    for (int nt = 0; nt < 2; nt++) {
        int n = n0w + nt * 16 + l16;
#pragma unroll
        for (int kq = 0; kq < 4; kq++) {
            int k = kq * 32 + quad * 8;
            bhi[nt][kq] = *(const bf16x8*)&Whi[n * HD + k];
            blo[nt][kq] = *(const bf16x8*)&Wlo[n * HD + k];
        }
    }

    // stage A: 2048 float4s, coalesced; each thread's channels fixed (c4)
    {
        int c4 = (tid & 31) * 4;
        float sc[4], sh[4];
        if (BNRELU) {
#pragma unroll
            for (int j = 0; j < 4; j++) {
                float mu  = pcolsum[c4 + j] * (1.0f / NN);
                float var = pcolsq[c4 + j] * (1.0f / NN) - mu * mu;
                float a = gamma[c4 + j] * rsqrtf(var + BN_EPS);
                sc[j] = a;
                sh[j] = beta[c4 + j] - a * mu;
            }
        }
#pragma unroll
        for (int i = 0; i < 8; i++) {
            int f = tid + i * 256;        // 0..2047
            int r = f >> 5;
            int row = r0 + r;
            float av[4] = { 0.f, 0.f, 0.f, 0.f };
            if (row < NN) {
                float4 v = *(const float4*)&A[row * HD + c4];
                av[0] = v.x; av[1] = v.y; av[2] = v.z; av[3] = v.w;
            }
            ushort4 hh, ll;
            unsigned short* hp = (unsigned short*)&hh;
            unsigned short* lp = (unsigned short*)&ll;
#pragma unroll
            for (int j = 0; j < 4; j++) {
                float a = av[j];
                if (BNRELU) a = fmaxf(fmaf(sc[j], a, sh[j]), 0.f);
                hp[j] = f2bf(a);
                lp[j] = f2bf(a - bf2f(hp[j]));
            }
            *(ushort4*)&AsH[r * AST + c4] = hh;
            *(ushort4*)&AsL[r * AST + c4] = ll;
        }
    }
    __syncthreads();

    f32x4 acc[4][2];
#pragma unroll
    for (int mt = 0; mt < 4; mt++)
#pragma unroll
        for (int nt = 0; nt < 2; nt++)
#pragma unroll
            for (int e = 0; e < 4; e++) acc[mt][nt][e] = 0.f;

#pragma unroll
    for (int mt = 0; mt < 4; mt++) {
        int mrow = mt * 16 + l16;
#pragma unroll
        for (int kq = 0; kq < 4; kq++) {
            int k = kq * 32 + quad * 8;
            bf16x8 ah = *(const bf16x8*)&AsH[mrow * AST + k];
            bf16x8 al = *(const bf16x8*)&AsL[mrow * AST + k];
#pragma unroll
            for (int nt = 0; nt < 2; nt++) {
                acc[mt][nt] = __builtin_amdgcn_mfma_f32_16x16x32_bf16(
                    ah, bhi[nt][kq], acc[mt][nt], 0, 0, 0);
                acc[mt][nt] = __builtin_amdgcn_mfma_f32_16x16x32_bf16(
                    ah, blo[nt][kq], acc[mt][nt], 0, 0, 0);
                acc[mt][nt] = __builtin_amdgcn_mfma_f32_16x16x32_bf16(
                    al, bhi[nt][kq], acc[mt][nt], 0, 0, 0);
            }
        }
    }

    float s[2] = { 0.f, 0.f }, q[2] = { 0.f, 0.f };
#pragma unroll
    for (int mt = 0; mt < 4; mt++) {
        int rbase = r0 + mt * 16 + quad * 4;
#pragma unroll
        for (int rr = 0; rr < 4; rr++) {
            int row = rbase + rr;
            if (row < NN) {
#pragma unroll
                for (int nt = 0; nt < 2; nt++) {
                    float v = acc[mt][nt][rr];
                    out[row * HD + n0w + nt * 16 + l16] = v;
                    s[nt] += v;
                    q[nt] = fmaf(v, v, q[nt]);
                }
            }
        }
    }
#pragma unroll
    for (int nt = 0; nt < 2; nt++) {
        float ss = s[nt], qq = q[nt];
        ss += __shfl_xor(ss, 16); ss += __shfl_xor(ss, 32);
        qq += __shfl_xor(qq, 16); qq += __shfl_xor(qq, 32);
        if (lane < 16) {
            atomicAdd(&colsum[n0w + nt * 16 + lane], ss);
            atomicAdd(&colsq[n0w + nt * 16 + lane], qq);
        }
    }
}

// ---------- pool + classifier: one block per graph, inline BN ----------
__global__ __launch_bounds__(256) void k_pool(
    const float* __restrict__ u,
    const float* __restrict__ pcolsum, const float* __restrict__ pcolsq,
    const float* __restrict__ gamma, const float* __restrict__ beta,
    const int* __restrict__ batch, const float* __restrict__ Wc,
    const float* __restrict__ bc, float* __restrict__ out) {
    __shared__ float part[2][HD];
    __shared__ float pooled[HD];
    __shared__ int range[2];
    int g = blockIdx.x;
    int tid = threadIdx.x;
    if (tid < 2) {
        int target = g + tid;
        int lo = 0, hi = NN;
        while (lo < hi) {
            int mid = (lo + hi) >> 1;
            if (batch[mid] < target) lo = mid + 1; else hi = mid;
        }
        range[tid] = lo;
    }
    __syncthreads();
    int start = range[0], end = range[1];
    int c    = tid & (HD - 1);
    int half = tid >> 7;
    float mu  = pcolsum[c] * (1.0f / NN);
    float var = pcolsq[c] * (1.0f / NN) - mu * mu;
    float sc = gamma[c] * rsqrtf(var + BN_EPS);
    float sh = beta[c] - sc * mu;
    float acc = 0.f;
    for (int n = start + half; n < end; n += 2)
        acc += fmaxf(fmaf(sc, u[n * HD + c], sh), 0.f);
    part[half][c] = acc;
    __syncthreads();
    if (tid < HD) {
        float inv = 1.0f / fmaxf((float)(end - start), 1.0f);
        pooled[tid] = (part[0][tid] + part[1][tid]) * inv;
    }
    __syncthreads();
    if (tid < NC) {
        float a = bc[tid];
        for (int k = 0; k < HD; k++)
            a = fmaf(pooled[k], Wc[k * NC + tid], a);
        out[g * NC + tid] = a;
    }
}

extern "C" void kernel_launch(void* const* d_in, const int* in_sizes, int n_in,
                              void* d_out, int out_size, void* d_ws, size_t ws_size,
                              hipStream_t stream) {
    const float* x      = (const float*)d_in[0];
    const int*   ei     = (const int*)d_in[1];
    const int*   batch  = (const int*)d_in[2];
    const float* enc_W  = (const float*)d_in[3];
    const float* enc_b  = (const float*)d_in[4];
    const float* W1     = (const float*)d_in[5];
    // d_in[6] = b1, d_in[10] = b2: cancel in the following BN (mean shift)
    const float* g1     = (const float*)d_in[7];
    const float* be1    = (const float*)d_in[8];
    const float* W2     = (const float*)d_in[9];
    const float* eps_g  = (const float*)d_in[11];
    const float* bn_g   = (const float*)d_in[12];
    const float* bn_b   = (const float*)d_in[13];
    const float* cls_W  = (const float*)d_in[14];
    const float* cls_b  = (const float*)d_in[15];
    float* out = (float*)d_out;

    float*          stats = (float*)d_ws;                       // 6 x (128 sum + 128 sq)
    unsigned short* Wt    = (unsigned short*)(stats + 6 * 256); // 12 x 128 x 128 bf16
    float* bufA = (float*)(Wt + 12 * HD * HD);                  // NN*HD fp32
    float* bufB = bufA + NN * HD;
    float* bufC = bufB + NN * HD;
    int* counts  = (int*)(bufC + NN * HD);                      // NN (also cursor)
    int* row_ptr = counts + NN;                                 // NN+1
    int* csr_src = row_ptr + NN + 1;                            // NE

    hipMemsetAsync(stats, 0, 6 * 256 * sizeof(float), stream);
    hipMemsetAsync(counts, 0, NN * sizeof(int), stream);

    dim3 b256(256);
    k_prep<<<(6 * 2048 + 255) / 256, b256, 0, stream>>>(W1, W2, Wt);
    k_hist<<<(NE + 255) / 256, b256, 0, stream>>>(ei, counts);
    k_scan<<<1, 1024, 0, stream>>>(counts, row_ptr, counts /*cursor*/);
    k_fill<<<(NE + 255) / 256, b256, 0, stream>>>(ei, counts, csr_src);
    k_enc<<<(NN * 32 + 255) / 256, b256, 0, stream>>>(x, enc_W, enc_b, bufA);

    const int aggr_blocks = (NN * 32 + 255) / 256;   // 2500
    const int gemm_blocks = (NN + 63) / 64;          // 313

    float* in = bufA;
    for (int l = 0; l < NL; l++) {
        float* st1 = stats + (2 * l) * 256;       // t stats
        float* st2 = stats + (2 * l + 1) * 256;   // u stats
        float* X = (l % 2 == 0) ? bufB : bufA;
        if (l == 0) {
            k_aggr<false><<<aggr_blocks, b256, 0, stream>>>(
                row_ptr, csr_src, in, nullptr, nullptr, nullptr, nullptr,
                eps_g, l, X);
        } else {
            float* stp = stats + (2 * (l - 1) + 1) * 256;
            k_aggr<true><<<aggr_blocks, b256, 0, stream>>>(
                row_ptr, csr_src, in, stp, stp + 128,
                bn_g + (l - 1) * HD, bn_b + (l - 1) * HD, eps_g, l, X);
        }
        k_gemm<false><<<gemm_blocks, b256, 0, stream>>>(
            X, Wt + (2 * l) * HD * HD, Wt + (6 + 2 * l) * HD * HD,
            nullptr, nullptr, nullptr, nullptr, bufC, st1, st1 + 128);
        k_gemm<true><<<gemm_blocks, b256, 0, stream>>>(
            bufC, Wt + (2 * l + 1) * HD * HD, Wt + (6 + 2 * l + 1) * HD * HD,
            st1, st1 + 128, g1 + l * HD, be1 + l * HD, X, st2, st2 + 128);
        in = X;
    }
    float* st5 = stats + 5 * 256;
    k_pool<<<NG, b256, 0, stream>>>(in, st5, st5 + 128,
                                    bn_g + 2 * HD, bn_b + 2 * HD,
                                    batch, cls_W, cls_b, out);
}

// Round 8
// 380.125 us; speedup vs baseline: 9.4814x; 1.1158x over previous
//
#include <hip/hip_runtime.h>

#define NN 20000
#define NE 640000
#define HD 128
#define NL 3
#define NG 128
#define NC 2
#define BN_EPS 1e-5f

typedef __attribute__((ext_vector_type(8))) short bf16x8;
typedef __attribute__((ext_vector_type(4))) float f32x4;
typedef __attribute__((ext_vector_type(8))) _Float16 f16x8;

__device__ __forceinline__ float bf2f(unsigned short u) {
    union { unsigned int i; float f; } x; x.i = ((unsigned int)u) << 16; return x.f;
}
__device__ __forceinline__ unsigned short f2bf(float f) {
    union { float f; unsigned int i; } x; x.f = f;
    unsigned int r = x.i + 0x7fffu + ((x.i >> 16) & 1u);
    return (unsigned short)(r >> 16);
}

// ---------- fused setup: weight split-prep + encoder + dst histogram ----------
// blocks [0,48): prep; [48,1298): enc (fp16 out); [1298,3798): hist
__global__ void k_setup(const float* __restrict__ x, const float* __restrict__ encW,
                        const float* __restrict__ encb,
                        const float* __restrict__ W1, const float* __restrict__ W2,
                        const int* __restrict__ ei,
                        unsigned short* __restrict__ Wt,
                        _Float16* __restrict__ h,
                        int* __restrict__ counts) {
    int b = blockIdx.x, tid = threadIdx.x;
    if (b < 48) {
        int t = b * 256 + tid;                 // 6*2048 = 12288
        if (t >= 6 * 2048) return;
        int mat = t >> 11;
        int rem = t & 2047;
        int n  = rem >> 4;
        int k0 = (rem & 15) * 8;
        int l  = mat >> 1;
        const float* src = (mat & 1) ? (W2 + l * HD * HD) : (W1 + l * HD * HD);
        unsigned short* dhi = Wt + mat * HD * HD;
        unsigned short* dlo = Wt + (6 + mat) * HD * HD;
        union { bf16x8 v; unsigned short u[8]; } hi, lo;
#pragma unroll
        for (int j = 0; j < 8; j++) {
            float w = src[(k0 + j) * HD + n];
            hi.u[j] = f2bf(w);
            lo.u[j] = f2bf(w - bf2f(hi.u[j]));
        }
        *(bf16x8*)&dhi[n * HD + k0] = hi.v;
        *(bf16x8*)&dlo[n * HD + k0] = lo.v;
    } else if (b < 48 + 1250) {
        int i = (b - 48) * 256 + tid;          // NN*16
        if (i >= NN * 16) return;
        int n  = i >> 4;
        int c8 = (i & 15) * 8;
        float xv = x[n];
        f16x8 o;
#pragma unroll
        for (int j = 0; j < 8; j++)
            o[j] = (_Float16)fmaf(xv, encW[c8 + j], encb[c8 + j]);
        *(f16x8*)&h[n * HD + c8] = o;
    } else {
        int e = (b - 1298) * 256 + tid;        // NE
        if (e >= NE) return;
        atomicAdd(&counts[ei[NE + e]], 1);
    }
}

// ---------- CSR scan ----------
__global__ __launch_bounds__(1024) void k_scan(const int* __restrict__ counts,
                                               int* __restrict__ row_ptr,
                                               int* __restrict__ cursor) {
    __shared__ int sdata[1024];
    int tid = threadIdx.x;
    int base = tid * 20;
    int loc[20];
    int run = 0;
#pragma unroll
    for (int j = 0; j < 20; j++) {
        int i = base + j;
        int v = (i < NN) ? counts[i] : 0;
        loc[j] = run;
        run += v;
    }
    sdata[tid] = run;
    __syncthreads();
    for (int off = 1; off < 1024; off <<= 1) {
        int t = (tid >= off) ? sdata[tid - off] : 0;
        __syncthreads();
        sdata[tid] += t;
        __syncthreads();
    }
    int excl = sdata[tid] - run;
#pragma unroll
    for (int j = 0; j < 20; j++) {
        int i = base + j;
        if (i < NN) {
            int o = excl + loc[j];
            row_ptr[i] = o;
            cursor[i]  = o;
        }
    }
    if (tid == 1023) row_ptr[NN] = NE;
}

__global__ void k_fill(const int* __restrict__ ei, int* __restrict__ cursor,
                       int* __restrict__ csr_src) {
    int e = blockIdx.x * blockDim.x + threadIdx.x;
    if (e >= NE) return;
    int pos = atomicAdd(&cursor[ei[NE + e]], 1);
    csr_src[pos] = ei[e];
}

// ---------- aggregation: fp16 gather, fp32 accumulate, fp32 out ----------
// APPLY: f(v) = relu(sc*v+sh), BN params computed inline from stats.
// 16 lanes per node (f16x8 = 16B/lane), 8-edge-deep gather unroll.
template <bool APPLY>
__global__ void k_aggr(const int* __restrict__ row_ptr, const int* __restrict__ csr_src,
                       const _Float16* __restrict__ u,
                       const float* __restrict__ pcolsum, const float* __restrict__ pcolsq,
                       const float* __restrict__ gamma, const float* __restrict__ beta,
                       const float* __restrict__ eps_gin, int l,
                       float* __restrict__ z) {
    int i = blockIdx.x * blockDim.x + threadIdx.x;   // NN*16
    if (i >= NN * 16) return;
    int n  = i >> 4;
    int c8 = (i & 15) * 8;
    float e = 1.0f + eps_gin[l];
    float sc[8], sh[8];
    if (APPLY) {
#pragma unroll
        for (int j = 0; j < 8; j++) {
            float mu  = pcolsum[c8 + j] * (1.0f / NN);
            float var = pcolsq[c8 + j] * (1.0f / NN) - mu * mu;
            float a = gamma[c8 + j] * rsqrtf(var + BN_EPS);
            sc[j] = a;
            sh[j] = beta[c8 + j] - a * mu;
        }
    }
    float acc[8];
    {
        f16x8 r = *(const f16x8*)&u[n * HD + c8];
#pragma unroll
        for (int j = 0; j < 8; j++) {
            float v = (float)r[j];
            if (APPLY) v = fmaxf(fmaf(sc[j], v, sh[j]), 0.f);
            acc[j] = e * v;
        }
    }
    int p = row_ptr[n], end = row_ptr[n + 1];
    for (; p + 7 < end; p += 8) {
        f16x8 r[8];
#pragma unroll
        for (int j = 0; j < 8; j++) r[j] = *(const f16x8*)&u[csr_src[p + j] * HD + c8];
#pragma unroll
        for (int j = 0; j < 8; j++)
#pragma unroll
            for (int q = 0; q < 8; q++) {
                float v = (float)r[j][q];
                if (APPLY) v = fmaxf(fmaf(sc[q], v, sh[q]), 0.f);
                acc[q] += v;
            }
    }
    for (; p < end; p++) {
        f16x8 r = *(const f16x8*)&u[csr_src[p] * HD + c8];
#pragma unroll
        for (int q = 0; q < 8; q++) {
            float v = (float)r[q];
            if (APPLY) v = fmaxf(fmaf(sc[q], v, sh[q]), 0.f);
            acc[q] += v;
        }
    }
    float4 o0 = { acc[0], acc[1], acc[2], acc[3] };
    float4 o1 = { acc[4], acc[5], acc[6], acc[7] };
    *(float4*)&z[n * HD + c8]     = o0;
    *(float4*)&z[n * HD + c8 + 4] = o1;
}

// ---------- split-bf16 MFMA GEMM, LDS-staged A ----------
// out = f(A_f32) @ W^T via Ahi*Whi + Ahi*Wlo + Alo*Whi (fp32-accurate).
// OUTF16: store fp16 (tensor is gathered next layer), else fp32.
#define AST 136
template <bool BNRELU, bool OUTF16>
__global__ __launch_bounds__(256) void k_gemm(
    const float* __restrict__ A, const unsigned short* __restrict__ Whi,
    const unsigned short* __restrict__ Wlo,
    const float* __restrict__ pcolsum, const float* __restrict__ pcolsq,
    const float* __restrict__ gamma, const float* __restrict__ beta,
    void* __restrict__ outv,
    float* __restrict__ colsum, float* __restrict__ colsq) {
    __shared__ __align__(16) unsigned short AsH[64 * AST];
    __shared__ __align__(16) unsigned short AsL[64 * AST];
    int tid  = threadIdx.x;
    int wave = tid >> 6, lane = tid & 63;
    int quad = lane >> 4, l16 = lane & 15;
    int r0   = blockIdx.x * 64;
    int n0w  = wave * 32;

    bf16x8 bhi[2][4], blo[2][4];
#pragma unroll
    for (int nt = 0; nt < 2; nt++) {
        int n = n0w + nt * 16 + l16;
#pragma unroll
        for (int kq = 0; kq < 4; kq++) {
            int k = kq * 32 + quad * 8;
            bhi[nt][kq] = *(const bf16x8*)&Whi[n * HD + k];
            blo[nt][kq] = *(const bf16x8*)&Wlo[n * HD + k];
        }
    }

    {
        int c4 = (tid & 31) * 4;
        float sc[4], sh[4];
        if (BNRELU) {
#pragma unroll
            for (int j = 0; j < 4; j++) {
                float mu  = pcolsum[c4 + j] * (1.0f / NN);
                float var = pcolsq[c4 + j] * (1.0f / NN) - mu * mu;
                float a = gamma[c4 + j] * rsqrtf(var + BN_EPS);
                sc[j] = a;
                sh[j] = beta[c4 + j] - a * mu;
            }
        }
#pragma unroll
        for (int i = 0; i < 8; i++) {
            int f = tid + i * 256;
            int r = f >> 5;
            int row = r0 + r;
            float av[4] = { 0.f, 0.f, 0.f, 0.f };
            if (row < NN) {
                float4 v = *(const float4*)&A[row * HD + c4];
                av[0] = v.x; av[1] = v.y; av[2] = v.z; av[3] = v.w;
            }
            ushort4 hh, ll;
            unsigned short* hp = (unsigned short*)&hh;
            unsigned short* lp = (unsigned short*)&ll;
#pragma unroll
            for (int j = 0; j < 4; j++) {
                float a = av[j];
                if (BNRELU) a = fmaxf(fmaf(sc[j], a, sh[j]), 0.f);
                hp[j] = f2bf(a);
                lp[j] = f2bf(a - bf2f(hp[j]));
            }
            *(ushort4*)&AsH[r * AST + c4] = hh;
            *(ushort4*)&AsL[r * AST + c4] = ll;
        }
    }
    __syncthreads();

    f32x4 acc[4][2];
#pragma unroll
    for (int mt = 0; mt < 4; mt++)
#pragma unroll
        for (int nt = 0; nt < 2; nt++)
#pragma unroll
            for (int e = 0; e < 4; e++) acc[mt][nt][e] = 0.f;

#pragma unroll
    for (int mt = 0; mt < 4; mt++) {
        int mrow = mt * 16 + l16;
#pragma unroll
        for (int kq = 0; kq < 4; kq++) {
            int k = kq * 32 + quad * 8;
            bf16x8 ah = *(const bf16x8*)&AsH[mrow * AST + k];
            bf16x8 al = *(const bf16x8*)&AsL[mrow * AST + k];
#pragma unroll
            for (int nt = 0; nt < 2; nt++) {
                acc[mt][nt] = __builtin_amdgcn_mfma_f32_16x16x32_bf16(
                    ah, bhi[nt][kq], acc[mt][nt], 0, 0, 0);
                acc[mt][nt] = __builtin_amdgcn_mfma_f32_16x16x32_bf16(
                    ah, blo[nt][kq], acc[mt][nt], 0, 0, 0);
                acc[mt][nt] = __builtin_amdgcn_mfma_f32_16x16x32_bf16(
                    al, bhi[nt][kq], acc[mt][nt], 0, 0, 0);
            }
        }
    }

    float s[2] = { 0.f, 0.f }, q[2] = { 0.f, 0.f };
#pragma unroll
    for (int mt = 0; mt < 4; mt++) {
        int rbase = r0 + mt * 16 + quad * 4;
#pragma unroll
        for (int rr = 0; rr < 4; rr++) {
            int row = rbase + rr;
            if (row < NN) {
#pragma unroll
                for (int nt = 0; nt < 2; nt++) {
                    float v = acc[mt][nt][rr];
                    int col = n0w + nt * 16 + l16;
                    if (OUTF16)
                        ((_Float16*)outv)[row * HD + col] = (_Float16)v;
                    else
                        ((float*)outv)[row * HD + col] = v;
                    s[nt] += v;
                    q[nt] = fmaf(v, v, q[nt]);
                }
            }
        }
    }
#pragma unroll
    for (int nt = 0; nt < 2; nt++) {
        float ss = s[nt], qq = q[nt];
        ss += __shfl_xor(ss, 16); ss += __shfl_xor(ss, 32);
        qq += __shfl_xor(qq, 16); qq += __shfl_xor(qq, 32);
        if (lane < 16) {
            atomicAdd(&colsum[n0w + nt * 16 + lane], ss);
            atomicAdd(&colsq[n0w + nt * 16 + lane], qq);
        }
    }
}

// ---------- pool + classifier (fp16 u, inline BN) ----------
__global__ __launch_bounds__(256) void k_pool(
    const _Float16* __restrict__ u,
    const float* __restrict__ pcolsum, const float* __restrict__ pcolsq,
    const float* __restrict__ gamma, const float* __restrict__ beta,
    const int* __restrict__ batch, const float* __restrict__ Wc,
    const float* __restrict__ bc, float* __restrict__ out) {
    __shared__ float part[2][HD];
    __shared__ float pooled[HD];
    __shared__ int range[2];
    int g = blockIdx.x;
    int tid = threadIdx.x;
    if (tid < 2) {
        int target = g + tid;
        int lo = 0, hi = NN;
        while (lo < hi) {
            int mid = (lo + hi) >> 1;
            if (batch[mid] < target) lo = mid + 1; else hi = mid;
        }
        range[tid] = lo;
    }
    __syncthreads();
    int start = range[0], end = range[1];
    int c    = tid & (HD - 1);
    int half = tid >> 7;
    float mu  = pcolsum[c] * (1.0f / NN);
    float var = pcolsq[c] * (1.0f / NN) - mu * mu;
    float sc = gamma[c] * rsqrtf(var + BN_EPS);
    float sh = beta[c] - sc * mu;
    float acc = 0.f;
    for (int n = start + half; n < end; n += 2)
        acc += fmaxf(fmaf(sc, (float)u[n * HD + c], sh), 0.f);
    part[half][c] = acc;
    __syncthreads();
    if (tid < HD) {
        float inv = 1.0f / fmaxf((float)(end - start), 1.0f);
        pooled[tid] = (part[0][tid] + part[1][tid]) * inv;
    }
    __syncthreads();
    if (tid < NC) {
        float a = bc[tid];
        for (int k = 0; k < HD; k++)
            a = fmaf(pooled[k], Wc[k * NC + tid], a);
        out[g * NC + tid] = a;
    }
}

extern "C" void kernel_launch(void* const* d_in, const int* in_sizes, int n_in,
                              void* d_out, int out_size, void* d_ws, size_t ws_size,
                              hipStream_t stream) {
    const float* x      = (const float*)d_in[0];
    const int*   ei     = (const int*)d_in[1];
    const int*   batch  = (const int*)d_in[2];
    const float* enc_W  = (const float*)d_in[3];
    const float* enc_b  = (const float*)d_in[4];
    const float* W1     = (const float*)d_in[5];
    // d_in[6] = b1, d_in[10] = b2: cancel in the following BN (mean shift)
    const float* g1     = (const float*)d_in[7];
    const float* be1    = (const float*)d_in[8];
    const float* W2     = (const float*)d_in[9];
    const float* eps_g  = (const float*)d_in[11];
    const float* bn_g   = (const float*)d_in[12];
    const float* bn_b   = (const float*)d_in[13];
    const float* cls_W  = (const float*)d_in[14];
    const float* cls_b  = (const float*)d_in[15];
    float* out = (float*)d_out;

    float* stats = (float*)d_ws;                                // 6 x (128 sum + 128 sq)
    float* bufZ  = stats + 6 * 256;                             // NN*HD fp32 (aggr out)
    float* bufT  = bufZ + NN * HD;                              // NN*HD fp32 (gemm1 out)
    unsigned short* Wt = (unsigned short*)(bufT + NN * HD);     // 12 x HD x HD bf16
    _Float16* bufU = (_Float16*)(Wt + 12 * HD * HD);            // NN*HD fp16 (gathered tensor)
    int* counts  = (int*)(bufU + NN * HD);                      // NN (also cursor)
    int* row_ptr = counts + NN;                                 // NN+1
    int* csr_src = row_ptr + NN + 1;                            // NE

    hipMemsetAsync(stats, 0, 6 * 256 * sizeof(float), stream);
    hipMemsetAsync(counts, 0, NN * sizeof(int), stream);

    dim3 b256(256);
    // fused prep + enc + hist
    k_setup<<<3798, b256, 0, stream>>>(x, enc_W, enc_b, W1, W2, ei, Wt, bufU, counts);
    k_scan<<<1, 1024, 0, stream>>>(counts, row_ptr, counts /*cursor*/);
    k_fill<<<(NE + 255) / 256, b256, 0, stream>>>(ei, counts, csr_src);

    const int aggr_blocks = (NN * 16 + 255) / 256;   // 1250
    const int gemm_blocks = (NN + 63) / 64;          // 313

    for (int l = 0; l < NL; l++) {
        float* st1 = stats + (2 * l) * 256;       // t stats
        float* st2 = stats + (2 * l + 1) * 256;   // u stats
        if (l == 0) {
            k_aggr<false><<<aggr_blocks, b256, 0, stream>>>(
                row_ptr, csr_src, bufU, nullptr, nullptr, nullptr, nullptr,
                eps_g, l, bufZ);
        } else {
            float* stp = stats + (2 * (l - 1) + 1) * 256;
            k_aggr<true><<<aggr_blocks, b256, 0, stream>>>(
                row_ptr, csr_src, bufU, stp, stp + 128,
                bn_g + (l - 1) * HD, bn_b + (l - 1) * HD, eps_g, l, bufZ);
        }
        k_gemm<false, false><<<gemm_blocks, b256, 0, stream>>>(
            bufZ, Wt + (2 * l) * HD * HD, Wt + (6 + 2 * l) * HD * HD,
            nullptr, nullptr, nullptr, nullptr, bufT, st1, st1 + 128);
        k_gemm<true, true><<<gemm_blocks, b256, 0, stream>>>(
            bufT, Wt + (2 * l + 1) * HD * HD, Wt + (6 + 2 * l + 1) * HD * HD,
            st1, st1 + 128, g1 + l * HD, be1 + l * HD, bufU, st2, st2 + 128);
    }
    float* st5 = stats + 5 * 256;
    k_pool<<<NG, b256, 0, stream>>>(bufU, st5, st5 + 128,
                                    bn_g + 2 * HD, bn_b + 2 * HD,
                                    batch, cls_W, cls_b, out);
}

// Round 9
// 365.373 us; speedup vs baseline: 9.8642x; 1.0404x over previous
//
#include <hip/hip_runtime.h>

#define NN 20000
#define NE 640000
#define HD 128
#define NL 3
#define NG 128
#define NC 2
#define BN_EPS 1e-5f

typedef __attribute__((ext_vector_type(8))) short bf16x8;
typedef __attribute__((ext_vector_type(4))) float f32x4;
typedef __attribute__((ext_vector_type(8))) _Float16 f16x8;

__device__ __forceinline__ float bf2f(unsigned short u) {
    union { unsigned int i; float f; } x; x.i = ((unsigned int)u) << 16; return x.f;
}
__device__ __forceinline__ unsigned short f2bf(float f) {
    union { float f; unsigned int i; } x; x.f = f;
    unsigned int r = x.i + 0x7fffu + ((x.i >> 16) & 1u);
    return (unsigned short)(r >> 16);
}

// ---------- fused setup: weight split-prep + encoder + dst histogram ----------
// blocks [0,48): prep; [48,1298): enc (fp16 out); [1298,3798): hist
__global__ void k_setup(const float* __restrict__ x, const float* __restrict__ encW,
                        const float* __restrict__ encb,
                        const float* __restrict__ W1, const float* __restrict__ W2,
                        const int* __restrict__ ei,
                        unsigned short* __restrict__ Wt,
                        _Float16* __restrict__ h,
                        int* __restrict__ counts) {
    int b = blockIdx.x, tid = threadIdx.x;
    if (b < 48) {
        int t = b * 256 + tid;                 // 6*2048 = 12288
        if (t >= 6 * 2048) return;
        int mat = t >> 11;
        int rem = t & 2047;
        int n  = rem >> 4;
        int k0 = (rem & 15) * 8;
        int l  = mat >> 1;
        const float* src = (mat & 1) ? (W2 + l * HD * HD) : (W1 + l * HD * HD);
        unsigned short* dhi = Wt + mat * HD * HD;
        unsigned short* dlo = Wt + (6 + mat) * HD * HD;
        union { bf16x8 v; unsigned short u[8]; } hi, lo;
#pragma unroll
        for (int j = 0; j < 8; j++) {
            float w = src[(k0 + j) * HD + n];
            hi.u[j] = f2bf(w);
            lo.u[j] = f2bf(w - bf2f(hi.u[j]));
        }
        *(bf16x8*)&dhi[n * HD + k0] = hi.v;
        *(bf16x8*)&dlo[n * HD + k0] = lo.v;
    } else if (b < 48 + 1250) {
        int i = (b - 48) * 256 + tid;          // NN*16
        if (i >= NN * 16) return;
        int n  = i >> 4;
        int c8 = (i & 15) * 8;
        float xv = x[n];
        f16x8 o;
#pragma unroll
        for (int j = 0; j < 8; j++)
            o[j] = (_Float16)fmaf(xv, encW[c8 + j], encb[c8 + j]);
        *(f16x8*)&h[n * HD + c8] = o;
    } else {
        int e = (b - 1298) * 256 + tid;        // NE
        if (e >= NE) return;
        atomicAdd(&counts[ei[NE + e]], 1);
    }
}

// ---------- CSR scan ----------
__global__ __launch_bounds__(1024) void k_scan(const int* __restrict__ counts,
                                               int* __restrict__ row_ptr,
                                               int* __restrict__ cursor) {
    __shared__ int sdata[1024];
    int tid = threadIdx.x;
    int base = tid * 20;
    int loc[20];
    int run = 0;
#pragma unroll
    for (int j = 0; j < 20; j++) {
        int i = base + j;
        int v = (i < NN) ? counts[i] : 0;
        loc[j] = run;
        run += v;
    }
    sdata[tid] = run;
    __syncthreads();
    for (int off = 1; off < 1024; off <<= 1) {
        int t = (tid >= off) ? sdata[tid - off] : 0;
        __syncthreads();
        sdata[tid] += t;
        __syncthreads();
    }
    int excl = sdata[tid] - run;
#pragma unroll
    for (int j = 0; j < 20; j++) {
        int i = base + j;
        if (i < NN) {
            int o = excl + loc[j];
            row_ptr[i] = o;
            cursor[i]  = o;
        }
    }
    if (tid == 1023) row_ptr[NN] = NE;
}

__global__ void k_fill(const int* __restrict__ ei, int* __restrict__ cursor,
                       int* __restrict__ csr_src) {
    int e = blockIdx.x * blockDim.x + threadIdx.x;
    if (e >= NE) return;
    int pos = atomicAdd(&cursor[ei[NE + e]], 1);
    csr_src[pos] = ei[e];
}

// ---------- aggregation: fp16 gather, fp32 accumulate, fp16 out ----------
// APPLY: f(v) = relu(sc*v+sh), BN params computed inline from stats.
template <bool APPLY>
__global__ void k_aggr(const int* __restrict__ row_ptr, const int* __restrict__ csr_src,
                       const _Float16* __restrict__ u,
                       const float* __restrict__ pcolsum, const float* __restrict__ pcolsq,
                       const float* __restrict__ gamma, const float* __restrict__ beta,
                       const float* __restrict__ eps_gin, int l,
                       _Float16* __restrict__ z) {
    int i = blockIdx.x * blockDim.x + threadIdx.x;   // NN*16
    if (i >= NN * 16) return;
    int n  = i >> 4;
    int c8 = (i & 15) * 8;
    float e = 1.0f + eps_gin[l];
    float sc[8], sh[8];
    if (APPLY) {
#pragma unroll
        for (int j = 0; j < 8; j++) {
            float mu  = pcolsum[c8 + j] * (1.0f / NN);
            float var = pcolsq[c8 + j] * (1.0f / NN) - mu * mu;
            float a = gamma[c8 + j] * rsqrtf(var + BN_EPS);
            sc[j] = a;
            sh[j] = beta[c8 + j] - a * mu;
        }
    }
    float acc[8];
    {
        f16x8 r = *(const f16x8*)&u[n * HD + c8];
#pragma unroll
        for (int j = 0; j < 8; j++) {
            float v = (float)r[j];
            if (APPLY) v = fmaxf(fmaf(sc[j], v, sh[j]), 0.f);
            acc[j] = e * v;
        }
    }
    int p = row_ptr[n], end = row_ptr[n + 1];
    for (; p + 7 < end; p += 8) {
        f16x8 r[8];
#pragma unroll
        for (int j = 0; j < 8; j++) r[j] = *(const f16x8*)&u[csr_src[p + j] * HD + c8];
#pragma unroll
        for (int j = 0; j < 8; j++)
#pragma unroll
            for (int q = 0; q < 8; q++) {
                float v = (float)r[j][q];
                if (APPLY) v = fmaxf(fmaf(sc[q], v, sh[q]), 0.f);
                acc[q] += v;
            }
    }
    for (; p < end; p++) {
        f16x8 r = *(const f16x8*)&u[csr_src[p] * HD + c8];
#pragma unroll
        for (int q = 0; q < 8; q++) {
            float v = (float)r[q];
            if (APPLY) v = fmaxf(fmaf(sc[q], v, sh[q]), 0.f);
            acc[q] += v;
        }
    }
    f16x8 o;
#pragma unroll
    for (int j = 0; j < 8; j++) o[j] = (_Float16)acc[j];
    *(f16x8*)&z[n * HD + c8] = o;
}

// ---------- split-bf16 MFMA GEMM, LDS-staged fp16 A ----------
// out_f16 = f(A_f16) @ W^T via Ahi*Whi + Ahi*Wlo + Alo*Whi.
// Split of an fp16 value into bf16 hi+lo is EXACT (11 mantissa bits <= 16).
// Stats (colsum/colsq) accumulated from fp32 accumulators pre-cast.
#define AST 136
template <bool BNRELU>
__global__ __launch_bounds__(256) void k_gemm(
    const _Float16* __restrict__ A, const unsigned short* __restrict__ Whi,
    const unsigned short* __restrict__ Wlo,
    const float* __restrict__ pcolsum, const float* __restrict__ pcolsq,
    const float* __restrict__ gamma, const float* __restrict__ beta,
    _Float16* __restrict__ out,
    float* __restrict__ colsum, float* __restrict__ colsq) {
    __shared__ __align__(16) unsigned short AsH[64 * AST];
    __shared__ __align__(16) unsigned short AsL[64 * AST];
    int tid  = threadIdx.x;
    int wave = tid >> 6, lane = tid & 63;
    int quad = lane >> 4, l16 = lane & 15;
    int r0   = blockIdx.x * 64;
    int n0w  = wave * 32;

    bf16x8 bhi[2][4], blo[2][4];
#pragma unroll
    for (int nt = 0; nt < 2; nt++) {
        int n = n0w + nt * 16 + l16;
#pragma unroll
        for (int kq = 0; kq < 4; kq++) {
            int k = kq * 32 + quad * 8;
            bhi[nt][kq] = *(const bf16x8*)&Whi[n * HD + k];
            blo[nt][kq] = *(const bf16x8*)&Wlo[n * HD + k];
        }
    }

    // stage A: 64 rows x 128 ch fp16, 16 B/thread/iter, 4 iters, coalesced
    {
        int c8 = (tid & 15) * 8;
        int rb = tid >> 4;                    // 0..15
        float sc[8], sh[8];
        if (BNRELU) {
#pragma unroll
            for (int j = 0; j < 8; j++) {
                float mu  = pcolsum[c8 + j] * (1.0f / NN);
                float var = pcolsq[c8 + j] * (1.0f / NN) - mu * mu;
                float a = gamma[c8 + j] * rsqrtf(var + BN_EPS);
                sc[j] = a;
                sh[j] = beta[c8 + j] - a * mu;
            }
        }
#pragma unroll
        for (int i = 0; i < 4; i++) {
            int r = rb + i * 16;
            int row = r0 + r;
            f16x8 v = (f16x8)(_Float16)0.f;
            if (row < NN) v = *(const f16x8*)&A[row * HD + c8];
            union { bf16x8 bv; unsigned short u[8]; } hh, ll;
#pragma unroll
            for (int j = 0; j < 8; j++) {
                float a = (float)v[j];
                if (BNRELU) a = fmaxf(fmaf(sc[j], a, sh[j]), 0.f);
                hh.u[j] = f2bf(a);
                ll.u[j] = f2bf(a - bf2f(hh.u[j]));
            }
            *(bf16x8*)&AsH[r * AST + c8] = hh.bv;
            *(bf16x8*)&AsL[r * AST + c8] = ll.bv;
        }
    }
    __syncthreads();

    f32x4 acc[4][2];
#pragma unroll
    for (int mt = 0; mt < 4; mt++)
#pragma unroll
        for (int nt = 0; nt < 2; nt++)
#pragma unroll
            for (int e = 0; e < 4; e++) acc[mt][nt][e] = 0.f;

#pragma unroll
    for (int mt = 0; mt < 4; mt++) {
        int mrow = mt * 16 + l16;
#pragma unroll
        for (int kq = 0; kq < 4; kq++) {
            int k = kq * 32 + quad * 8;
            bf16x8 ah = *(const bf16x8*)&AsH[mrow * AST + k];
            bf16x8 al = *(const bf16x8*)&AsL[mrow * AST + k];
#pragma unroll
            for (int nt = 0; nt < 2; nt++) {
                acc[mt][nt] = __builtin_amdgcn_mfma_f32_16x16x32_bf16(
                    ah, bhi[nt][kq], acc[mt][nt], 0, 0, 0);
                acc[mt][nt] = __builtin_amdgcn_mfma_f32_16x16x32_bf16(
                    ah, blo[nt][kq], acc[mt][nt], 0, 0, 0);
                acc[mt][nt] = __builtin_amdgcn_mfma_f32_16x16x32_bf16(
                    al, bhi[nt][kq], acc[mt][nt], 0, 0, 0);
            }
        }
    }

    float s[2] = { 0.f, 0.f }, q[2] = { 0.f, 0.f };
#pragma unroll
    for (int mt = 0; mt < 4; mt++) {
        int rbase = r0 + mt * 16 + quad * 4;
#pragma unroll
        for (int rr = 0; rr < 4; rr++) {
            int row = rbase + rr;
            if (row < NN) {
#pragma unroll
                for (int nt = 0; nt < 2; nt++) {
                    float v = acc[mt][nt][rr];
                    out[row * HD + n0w + nt * 16 + l16] = (_Float16)v;
                    s[nt] += v;
                    q[nt] = fmaf(v, v, q[nt]);
                }
            }
        }
    }
#pragma unroll
    for (int nt = 0; nt < 2; nt++) {
        float ss = s[nt], qq = q[nt];
        ss += __shfl_xor(ss, 16); ss += __shfl_xor(ss, 32);
        qq += __shfl_xor(qq, 16); qq += __shfl_xor(qq, 32);
        if (lane < 16) {
            atomicAdd(&colsum[n0w + nt * 16 + lane], ss);
            atomicAdd(&colsq[n0w + nt * 16 + lane], qq);
        }
    }
}

// ---------- pool + classifier (fp16 u, inline BN) ----------
__global__ __launch_bounds__(256) void k_pool(
    const _Float16* __restrict__ u,
    const float* __restrict__ pcolsum, const float* __restrict__ pcolsq,
    const float* __restrict__ gamma, const float* __restrict__ beta,
    const int* __restrict__ batch, const float* __restrict__ Wc,
    const float* __restrict__ bc, float* __restrict__ out) {
    __shared__ float part[2][HD];
    __shared__ float pooled[HD];
    __shared__ int range[2];
    int g = blockIdx.x;
    int tid = threadIdx.x;
    if (tid < 2) {
        int target = g + tid;
        int lo = 0, hi = NN;
        while (lo < hi) {
            int mid = (lo + hi) >> 1;
            if (batch[mid] < target) lo = mid + 1; else hi = mid;
        }
        range[tid] = lo;
    }
    __syncthreads();
    int start = range[0], end = range[1];
    int c    = tid & (HD - 1);
    int half = tid >> 7;
    float mu  = pcolsum[c] * (1.0f / NN);
    float var = pcolsq[c] * (1.0f / NN) - mu * mu;
    float sc = gamma[c] * rsqrtf(var + BN_EPS);
    float sh = beta[c] - sc * mu;
    float acc = 0.f;
    for (int n = start + half; n < end; n += 2)
        acc += fmaxf(fmaf(sc, (float)u[n * HD + c], sh), 0.f);
    part[half][c] = acc;
    __syncthreads();
    if (tid < HD) {
        float inv = 1.0f / fmaxf((float)(end - start), 1.0f);
        pooled[tid] = (part[0][tid] + part[1][tid]) * inv;
    }
    __syncthreads();
    if (tid < NC) {
        float a = bc[tid];
        for (int k = 0; k < HD; k++)
            a = fmaf(pooled[k], Wc[k * NC + tid], a);
        out[g * NC + tid] = a;
    }
}

extern "C" void kernel_launch(void* const* d_in, const int* in_sizes, int n_in,
                              void* d_out, int out_size, void* d_ws, size_t ws_size,
                              hipStream_t stream) {
    const float* x      = (const float*)d_in[0];
    const int*   ei     = (const int*)d_in[1];
    const int*   batch  = (const int*)d_in[2];
    const float* enc_W  = (const float*)d_in[3];
    const float* enc_b  = (const float*)d_in[4];
    const float* W1     = (const float*)d_in[5];
    // d_in[6] = b1, d_in[10] = b2: cancel in the following BN (mean shift)
    const float* g1     = (const float*)d_in[7];
    const float* be1    = (const float*)d_in[8];
    const float* W2     = (const float*)d_in[9];
    const float* eps_g  = (const float*)d_in[11];
    const float* bn_g   = (const float*)d_in[12];
    const float* bn_b   = (const float*)d_in[13];
    const float* cls_W  = (const float*)d_in[14];
    const float* cls_b  = (const float*)d_in[15];
    float* out = (float*)d_out;

    // 16B-aligned large arrays first
    unsigned short* Wt = (unsigned short*)d_ws;                 // 12 x HD x HD bf16
    _Float16* bufZ = (_Float16*)(Wt + 12 * HD * HD);            // NN*HD fp16 (aggr out)
    _Float16* bufT = bufZ + NN * HD;                            // NN*HD fp16 (gemm1 out)
    _Float16* bufU = bufT + NN * HD;                            // NN*HD fp16 (gathered)
    float* stats  = (float*)(bufU + NN * HD);                   // 6 x 256 f32
    int* counts   = (int*)(stats + 6 * 256);                    // NN (also cursor)
    int* row_ptr  = counts + NN;                                // NN+1
    int* csr_src  = row_ptr + NN + 1;                           // NE

    // stats + counts are contiguous: one memset
    hipMemsetAsync(stats, 0, (6 * 256 + NN) * sizeof(int), stream);

    dim3 b256(256);
    k_setup<<<3798, b256, 0, stream>>>(x, enc_W, enc_b, W1, W2, ei, Wt, bufU, counts);
    k_scan<<<1, 1024, 0, stream>>>(counts, row_ptr, counts /*cursor*/);
    k_fill<<<(NE + 255) / 256, b256, 0, stream>>>(ei, counts, csr_src);

    const int aggr_blocks = (NN * 16 + 255) / 256;   // 1250
    const int gemm_blocks = (NN + 63) / 64;          // 313

    for (int l = 0; l < NL; l++) {
        float* st1 = stats + (2 * l) * 256;       // t stats
        float* st2 = stats + (2 * l + 1) * 256;   // u stats
        if (l == 0) {
            k_aggr<false><<<aggr_blocks, b256, 0, stream>>>(
                row_ptr, csr_src, bufU, nullptr, nullptr, nullptr, nullptr,
                eps_g, l, bufZ);
        } else {
            float* stp = stats + (2 * (l - 1) + 1) * 256;
            k_aggr<true><<<aggr_blocks, b256, 0, stream>>>(
                row_ptr, csr_src, bufU, stp, stp + 128,
                bn_g + (l - 1) * HD, bn_b + (l - 1) * HD, eps_g, l, bufZ);
        }
        k_gemm<false><<<gemm_blocks, b256, 0, stream>>>(
            bufZ, Wt + (2 * l) * HD * HD, Wt + (6 + 2 * l) * HD * HD,
            nullptr, nullptr, nullptr, nullptr, bufT, st1, st1 + 128);
        k_gemm<true><<<gemm_blocks, b256, 0, stream>>>(
            bufT, Wt + (2 * l + 1) * HD * HD, Wt + (6 + 2 * l + 1) * HD * HD,
            st1, st1 + 128, g1 + l * HD, be1 + l * HD, bufU, st2, st2 + 128);
    }
    float* st5 = stats + 5 * 256;
    k_pool<<<NG, b256, 0, stream>>>(bufU, st5, st5 + 128,
                                    bn_g + 2 * HD, bn_b + 2 * HD,
                                    batch, cls_W, cls_b, out);
}